// Round 4
// baseline (458.759 us; speedup 1.0000x reference)
//
#include <hip/hip_runtime.h>
#include <cstdint>
#include <cstddef>

// BitLlamaAttention: B=1, S=2048, HIDDEN=2048, NH=16, HD=128, GROUP=128
// Inputs fp32 (probe-confirmed r1/r2). OUTPUT fp32 (r3 discriminator: r2==r3
// absmax identical => GEMM cores equal; 2.367 signature == bf16-written-into-
// fp32-read buffer; "bf16" in harness label is template-hardcoded).
//
// Pipeline (identical to r2 except final GEMM writes fp32):
//   0) dtype probe -> flag   1) x -> bf16
//   2) ternary group-quant wq/wk/wv/wo -> bf16 (fp32 thresholding)
//   3) q_proj/k_proj fp32; v_t bf16 transposed [o][t]
//   4) rope -> q_r,k_r bf16 [h][s][128]
//   5) scores = q_r k_r^T / sqrt(128) (causal tile skip)
//   6) causal softmax (zero-fills diag-tile tail)
//   7) attn = probs @ v_t^T (K limited to (by+1)*128)
//   8) d_out(fp32) = attn @ wo_q^T     <-- OM=0 now
//
// GEMM core: 128x128 tile, BK=64, 4 waves, mfma_f32_16x16x32_bf16,
// global_load_lds width=16, XOR chunk swizzle. Verified equal to an
// independent VALU reference core in r2/r3.

typedef __attribute__((ext_vector_type(8))) short bf16x8;
typedef __attribute__((ext_vector_type(4))) float f32x4;
typedef __attribute__((address_space(3))) void lds_void;
typedef const __attribute__((address_space(1))) void gmem_void;

__device__ __forceinline__ short f2bf(float x) {
    union { float f; uint32_t u; } c; c.f = x;
    uint32_t r = (c.u + 0x7FFFu + ((c.u >> 16) & 1u)) >> 16;
    return (short)r;
}
__device__ __forceinline__ float bf2f(short x) {
    union { uint32_t u; float f; } c; c.u = ((uint32_t)(uint16_t)x) << 16;
    return c.f;
}

// ------------------------------------------------------------ dtype probe
__global__ __launch_bounds__(64) void zero_flag(int* f) {
    if (threadIdx.x == 0) *f = 0;
}

__global__ __launch_bounds__(256) void detect_kernel(
    const unsigned short* __restrict__ p, int n, int* __restrict__ flag)
{
    int tid = blockIdx.x * 256 + threadIdx.x;
    int cnt = 0;
    for (int i = tid; i < n; i += 65536) {
        int e = (p[i] >> 7) & 0xFF;
        cnt += (e >= 0xF0) ? 1 : 0;
    }
#pragma unroll
    for (int off = 1; off < 64; off <<= 1) cnt += __shfl_xor(cnt, off);
    if ((threadIdx.x & 63) == 0 && cnt) atomicAdd(flag, cnt);
}

__global__ __launch_bounds__(256) void convert_kernel(
    const void* __restrict__ in, short* __restrict__ out, int n,
    const int* __restrict__ flag)
{
    bool isf32 = (*flag > 1000);
    int i = blockIdx.x * 256 + threadIdx.x;
    if (i >= n) return;
    out[i] = isf32 ? f2bf(((const float*)in)[i]) : ((const short*)in)[i];
}

// ---------------------------------------------------------------- quantize
__global__ __launch_bounds__(256) void quant_kernel(
    const void* __restrict__ w0, const void* __restrict__ w1,
    const void* __restrict__ w2, const void* __restrict__ w3,
    short* __restrict__ q0, short* __restrict__ q1,
    short* __restrict__ q2, short* __restrict__ q3,
    const int* __restrict__ flag)
{
    bool isf32 = (*flag > 1000);
    int gw   = blockIdx.x * 4 + (threadIdx.x >> 6);
    int lane = threadIdx.x & 63;
    int mat  = gw >> 15;
    int g    = gw & 32767;
    const void* w = (mat == 0) ? w0 : (mat == 1) ? w1 : (mat == 2) ? w2 : w3;
    short*      q = (mat == 0) ? q0 : (mat == 1) ? q1 : (mat == 2) ? q2 : q3;
    int idx = g * 64 + lane;                       // index of element PAIR
    float a, b;
    if (isf32) {
        const float* wf = (const float*)w;
        a = wf[idx * 2]; b = wf[idx * 2 + 1];
    } else {
        int pr = ((const int*)w)[idx];
        a = bf2f((short)(pr & 0xFFFF));
        b = bf2f((short)(((uint32_t)pr) >> 16));
    }
    float s = fabsf(a) + fabsf(b);
#pragma unroll
    for (int off = 1; off < 64; off <<= 1) s += __shfl_xor(s, off);
    float scale = fmaxf(s * (1.0f / 128.0f), 1e-8f);
    float na = a / scale, nb = b / scale;
    float ra = (na > 0.5f) ? scale : (na < -0.5f) ? -scale : 0.0f;
    float rb = (nb > 0.5f) ? scale : (nb < -0.5f) ? -scale : 0.0f;
    ((int*)q)[idx] = (int)(uint16_t)f2bf(ra) | ((int)(uint16_t)f2bf(rb) << 16);
}

// ---------------------------------------------------------------- GEMM (B^T)
// C[m,n] = scale * sum_k A[m,k]*B[n,k];  A:(M,K,lda) B:(N,K,ldb) bf16 K-major.
// OM: 0 = fp32 C[row*ldc+col]; 1 = bf16 same; 2 = bf16 C[col*ldc+row].
// CSKIP: skip bx>by tiles. CK: K limited to (by+1)*128.
template<int OM, bool CSKIP, bool CK>
__global__ __launch_bounds__(256) void gemm_bt(
    const short* __restrict__ A, const short* __restrict__ B, void* __restrict__ C,
    int M, int N, int K, int lda, int ldb, int ldc, float scale,
    long long sA, long long sB, long long sC)
{
    int bx = blockIdx.x, by = blockIdx.y, bz = blockIdx.z;
    if (CSKIP && bx > by) return;
    const short* Ab = A + (long long)bz * sA + (long long)by * 128 * lda;
    const short* Bb = B + (long long)bz * sB + (long long)bx * 128 * ldb;
    __shared__ short lA[128 * 64];
    __shared__ short lB[128 * 64];
    int tid = threadIdx.x;
    int lane = tid & 63, wv = tid >> 6;
    int Kend = K;
    if (CK) { int kl = (by + 1) * 128; Kend = kl < K ? kl : K; }
    f32x4 acc[4][4];
#pragma unroll
    for (int i = 0; i < 4; i++)
#pragma unroll
        for (int j = 0; j < 4; j++)
#pragma unroll
            for (int r = 0; r < 4; r++) acc[i][j][r] = 0.0f;

    int rbase = (wv >> 1) * 64, cbase = (wv & 1) * 64;

    for (int k0 = 0; k0 < Kend; k0 += 64) {
        __syncthreads();
#pragma unroll
        for (int i = 0; i < 4; i++) {
            int ci  = i * 256 + tid;
            int row = ci >> 3;
            int kcG = (ci & 7) ^ (row & 7);        // XOR swizzle
            const short* gp = Ab + (long long)row * lda + k0 + kcG * 8;
            __builtin_amdgcn_global_load_lds((gmem_void*)gp, (lds_void*)(lA + ci * 8), 16, 0, 0);
        }
#pragma unroll
        for (int i = 0; i < 4; i++) {
            int ci  = i * 256 + tid;
            int row = ci >> 3;
            int kcG = (ci & 7) ^ (row & 7);
            const short* gp = Bb + (long long)row * ldb + k0 + kcG * 8;
            __builtin_amdgcn_global_load_lds((gmem_void*)gp, (lds_void*)(lB + ci * 8), 16, 0, 0);
        }
        __syncthreads();
#pragma unroll
        for (int kk = 0; kk < 2; kk++) {
            int kc = kk * 4 + (lane >> 4);          // k-chunk for this quad
            bf16x8 a[4], b[4];
#pragma unroll
            for (int t = 0; t < 4; t++) {
                int r = rbase + t * 16 + (lane & 15);
                a[t] = *(const bf16x8*)(lA + (r * 8 + (kc ^ (r & 7))) * 8);
            }
#pragma unroll
            for (int t = 0; t < 4; t++) {
                int r = cbase + t * 16 + (lane & 15);
                b[t] = *(const bf16x8*)(lB + (r * 8 + (kc ^ (r & 7))) * 8);
            }
#pragma unroll
            for (int mt = 0; mt < 4; mt++)
#pragma unroll
                for (int nt = 0; nt < 4; nt++)
                    acc[mt][nt] = __builtin_amdgcn_mfma_f32_16x16x32_bf16(a[mt], b[nt], acc[mt][nt], 0, 0, 0);
        }
    }

    // epilogue: verified C/D map col=lane&15, row=(lane>>4)*4+reg
    int rq = (lane >> 4) * 4, cq = lane & 15;
#pragma unroll
    for (int mt = 0; mt < 4; mt++) {
#pragma unroll
        for (int nt = 0; nt < 4; nt++) {
#pragma unroll
            for (int r = 0; r < 4; r++) {
                int row = by * 128 + rbase + mt * 16 + rq + r;
                int col = bx * 128 + cbase + nt * 16 + cq;
                float v = acc[mt][nt][r] * scale;
                if (OM == 0) {
                    float* Cp = (float*)C + (long long)bz * sC;
                    Cp[(long long)row * ldc + col] = v;
                } else if (OM == 1) {
                    short* Cp = (short*)C + (long long)bz * sC;
                    Cp[(long long)row * ldc + col] = f2bf(v);
                } else {
                    short* Cp = (short*)C + (long long)bz * sC;
                    Cp[(long long)col * ldc + row] = f2bf(v);
                }
            }
        }
    }
}

// ---------------------------------------------------------------- RoPE
__global__ __launch_bounds__(256) void rope_kernel(
    const float* __restrict__ qp, const float* __restrict__ kp,
    short* __restrict__ qr, short* __restrict__ kr)
{
    int idx = blockIdx.x * 256 + threadIdx.x;      // 2048*16*64 = 2M
    int d = idx & 63;
    int h = (idx >> 6) & 15;
    int s = idx >> 10;
    float inv = exp2f((float)d * -0.20762050593261719f); // 10000^(-d/64)
    float ang = (float)s * inv;
    float sn, c;
    sincosf(ang, &sn, &c);
    long long io = (long long)s * 2048 + h * 128 + d;
    long long oo = (long long)h * 262144 + (long long)s * 128 + d;
    float x1 = qp[io], x2 = qp[io + 64];
    qr[oo]      = f2bf(x1 * c - x2 * sn);
    qr[oo + 64] = f2bf(x1 * sn + x2 * c);
    x1 = kp[io]; x2 = kp[io + 64];
    kr[oo]      = f2bf(x1 * c - x2 * sn);
    kr[oo + 64] = f2bf(x1 * sn + x2 * c);
}

// ---------------------------------------------------------------- softmax
__global__ __launch_bounds__(256) void softmax_kernel(short* __restrict__ sc)
{
    int s = blockIdx.x, h = blockIdx.y;
    short* row = sc + (long long)h * 4194304 + (long long)s * 2048;
    int n = s + 1;
    int tileEnd = ((s >> 7) + 1) << 7;
    int tid = threadIdx.x;
    int lane = tid & 63, wv = tid >> 6;
    __shared__ float red[4];
    float v[8];
    float m = -1e30f;
#pragma unroll
    for (int i = 0; i < 8; i++) {
        int t = tid + i * 256;
        float x = -1e30f;
        if (t < n) x = bf2f(row[t]);
        v[i] = x;
        m = fmaxf(m, x);
    }
#pragma unroll
    for (int off = 1; off < 64; off <<= 1) m = fmaxf(m, __shfl_xor(m, off));
    if (lane == 0) red[wv] = m;
    __syncthreads();
    m = fmaxf(fmaxf(red[0], red[1]), fmaxf(red[2], red[3]));
    float sum = 0.0f;
#pragma unroll
    for (int i = 0; i < 8; i++) {
        int t = tid + i * 256;
        float e = 0.0f;
        if (t < n) e = __expf(v[i] - m);
        v[i] = e;
        sum += e;
    }
#pragma unroll
    for (int off = 1; off < 64; off <<= 1) sum += __shfl_xor(sum, off);
    __syncthreads();
    if (lane == 0) red[wv] = sum;
    __syncthreads();
    sum = red[0] + red[1] + red[2] + red[3];
    float rinv = 1.0f / sum;
#pragma unroll
    for (int i = 0; i < 8; i++) {
        int t = tid + i * 256;
        if (t < tileEnd) row[t] = f2bf(v[i] * rinv);
    }
}

// ---------------------------------------------------------------- launch
extern "C" void kernel_launch(void* const* d_in, const int* in_sizes, int n_in,
                              void* d_out, int out_size, void* d_ws, size_t ws_size,
                              hipStream_t stream)
{
    const void* x  = d_in[0];
    const void* wq = d_in[2];
    const void* wk = d_in[3];
    const void* wv = d_in[4];
    const void* wo = d_in[5];

    char* ws = (char*)d_ws;
    size_t off = 0;
    auto alloc = [&](size_t b) { void* p = ws + off; off += (b + 255) & ~(size_t)255; return p; };
    short* wq_q   = (short*)alloc(8388608);
    short* wk_q   = (short*)alloc(8388608);
    short* wv_q   = (short*)alloc(8388608);
    short* wo_q   = (short*)alloc(8388608);
    float* q_proj = (float*)alloc(16777216);
    float* k_proj = (float*)alloc(16777216);
    short* v_t    = (short*)alloc(8388608);    // [o=2048][t=2048]
    short* q_r    = (short*)alloc(8388608);    // [h][s][128]
    short* k_r    = (short*)alloc(8388608);
    short* sc     = (short*)alloc(134217728);  // [h][s][t] bf16
    short* attn   = (short*)alloc(8388608);    // [s][h*128+d]
    short* x_bf   = (short*)alloc(8388608);
    int*   flag   = (int*)alloc(256);
    if (off > ws_size) return;

    zero_flag<<<1, 64, 0, stream>>>(flag);
    detect_kernel<<<256, 256, 0, stream>>>(
        (const unsigned short*)x, in_sizes[0], flag);
    convert_kernel<<<16384, 256, 0, stream>>>(x, x_bf, 4194304, flag);

    quant_kernel<<<32768, 256, 0, stream>>>(wq, wk, wv, wo,
                                            wq_q, wk_q, wv_q, wo_q, flag);

    gemm_bt<0,false,false><<<dim3(16,16,1), 256, 0, stream>>>(
        x_bf, wq_q, q_proj, 2048,2048,2048, 2048,2048,2048, 1.0f, 0,0,0);
    gemm_bt<0,false,false><<<dim3(16,16,1), 256, 0, stream>>>(
        x_bf, wk_q, k_proj, 2048,2048,2048, 2048,2048,2048, 1.0f, 0,0,0);
    gemm_bt<2,false,false><<<dim3(16,16,1), 256, 0, stream>>>(
        x_bf, wv_q, v_t,    2048,2048,2048, 2048,2048,2048, 1.0f, 0,0,0);

    rope_kernel<<<8192, 256, 0, stream>>>(q_proj, k_proj, q_r, k_r);

    gemm_bt<1,true,false><<<dim3(16,16,16), 256, 0, stream>>>(
        q_r, k_r, sc, 2048,2048,128, 128,128,2048,
        0.08838834764831845f, 262144LL, 262144LL, 4194304LL);

    softmax_kernel<<<dim3(2048,16), 256, 0, stream>>>(sc);

    gemm_bt<1,false,true><<<dim3(1,16,16), 256, 0, stream>>>(
        sc, v_t, attn, 2048,128,2048, 2048,2048,2048, 1.0f,
        4194304LL, 262144LL, 128LL);

    // FINAL: fp32 output into d_out (the r3 discriminator's conclusion)
    gemm_bt<0,false,false><<<dim3(16,16,1), 256, 0, stream>>>(
        attn, wo_q, d_out, 2048,2048,2048, 2048,2048,2048, 1.0f, 0,0,0);
}

// Round 5
// 381.968 us; speedup vs baseline: 1.2010x; 1.2010x over previous
//
#include <hip/hip_runtime.h>
#include <cstdint>
#include <cstddef>

// BitLlamaAttention: B=1, S=2048, HIDDEN=2048, NH=16, HD=128, GROUP=128
// Inputs fp32, output fp32 (established r1-r4). r4 passed at 458 us.
//
// r5: (a) flash-fused attention (kills 128 MB score tensor + 53us softmax),
//     (b) fused QKV projection GEMM (2048x6144, 768 blocks).
//
// Pipeline:
//   0) dtype probe -> flag   1) x -> bf16
//   2) ternary group-quant -> wqkv_q [6144][2048] bf16 (q,k,v stacked) + wo_q
//   3) gemm_bt<0> grid(48,16): qkv = x_bf @ wqkv_q^T  fp32 [2048][6144]
//   4) rope: q,k slices of qkv -> q_r,k_r bf16 [h][s][128]
//   5) vtrans: v slice -> v_t bf16 [o=2048][t=2048]
//   6) flash_kernel grid(16 qt,16 h): online-softmax attention -> attn bf16 [s][2048]
//   7) gemm_bt<0> grid(16,16): d_out(fp32) = attn @ wo_q^T
//
// GEMM core: 128x128 tile, BK=64, 4 waves, mfma_f32_16x16x32_bf16,
// global_load_lds width=16, XOR chunk swizzle (verified r2/r3 vs VALU ref).

typedef __attribute__((ext_vector_type(8))) short bf16x8;
typedef __attribute__((ext_vector_type(4))) float f32x4;
typedef __attribute__((address_space(3))) void lds_void;
typedef const __attribute__((address_space(1))) void gmem_void;

__device__ __forceinline__ short f2bf(float x) {
    union { float f; uint32_t u; } c; c.f = x;
    uint32_t r = (c.u + 0x7FFFu + ((c.u >> 16) & 1u)) >> 16;
    return (short)r;
}
__device__ __forceinline__ float bf2f(short x) {
    union { uint32_t u; float f; } c; c.u = ((uint32_t)(uint16_t)x) << 16;
    return c.f;
}

// ------------------------------------------------------------ dtype probe
__global__ __launch_bounds__(64) void zero_flag(int* f) {
    if (threadIdx.x == 0) *f = 0;
}

__global__ __launch_bounds__(256) void detect_kernel(
    const unsigned short* __restrict__ p, int n, int* __restrict__ flag)
{
    int tid = blockIdx.x * 256 + threadIdx.x;
    int cnt = 0;
    for (int i = tid; i < n; i += 65536) {
        int e = (p[i] >> 7) & 0xFF;
        cnt += (e >= 0xF0) ? 1 : 0;
    }
#pragma unroll
    for (int off = 1; off < 64; off <<= 1) cnt += __shfl_xor(cnt, off);
    if ((threadIdx.x & 63) == 0 && cnt) atomicAdd(flag, cnt);
}

__global__ __launch_bounds__(256) void convert_kernel(
    const void* __restrict__ in, short* __restrict__ out, int n,
    const int* __restrict__ flag)
{
    bool isf32 = (*flag > 1000);
    int i = blockIdx.x * 256 + threadIdx.x;
    if (i >= n) return;
    out[i] = isf32 ? f2bf(((const float*)in)[i]) : ((const short*)in)[i];
}

// ---------------------------------------------------------------- quantize
__global__ __launch_bounds__(256) void quant_kernel(
    const void* __restrict__ w0, const void* __restrict__ w1,
    const void* __restrict__ w2, const void* __restrict__ w3,
    short* __restrict__ q0, short* __restrict__ q1,
    short* __restrict__ q2, short* __restrict__ q3,
    const int* __restrict__ flag)
{
    bool isf32 = (*flag > 1000);
    int gw   = blockIdx.x * 4 + (threadIdx.x >> 6);
    int lane = threadIdx.x & 63;
    int mat  = gw >> 15;
    int g    = gw & 32767;
    const void* w = (mat == 0) ? w0 : (mat == 1) ? w1 : (mat == 2) ? w2 : w3;
    short*      q = (mat == 0) ? q0 : (mat == 1) ? q1 : (mat == 2) ? q2 : q3;
    int idx = g * 64 + lane;                       // index of element PAIR
    float a, b;
    if (isf32) {
        const float* wf = (const float*)w;
        a = wf[idx * 2]; b = wf[idx * 2 + 1];
    } else {
        int pr = ((const int*)w)[idx];
        a = bf2f((short)(pr & 0xFFFF));
        b = bf2f((short)(((uint32_t)pr) >> 16));
    }
    float s = fabsf(a) + fabsf(b);
#pragma unroll
    for (int off = 1; off < 64; off <<= 1) s += __shfl_xor(s, off);
    float scale = fmaxf(s * (1.0f / 128.0f), 1e-8f);
    float na = a / scale, nb = b / scale;
    float ra = (na > 0.5f) ? scale : (na < -0.5f) ? -scale : 0.0f;
    float rb = (nb > 0.5f) ? scale : (nb < -0.5f) ? -scale : 0.0f;
    ((int*)q)[idx] = (int)(uint16_t)f2bf(ra) | ((int)(uint16_t)f2bf(rb) << 16);
}

// ---------------------------------------------------------------- GEMM (B^T)
// C[m,n] = scale * sum_k A[m,k]*B[n,k];  A:(M,K,lda) B:(N,K,ldb) bf16 K-major.
// OM: 0 = fp32 C[row*ldc+col]; 1 = bf16 same; 2 = bf16 C[col*ldc+row].
template<int OM, bool CSKIP, bool CK>
__global__ __launch_bounds__(256) void gemm_bt(
    const short* __restrict__ A, const short* __restrict__ B, void* __restrict__ C,
    int M, int N, int K, int lda, int ldb, int ldc, float scale,
    long long sA, long long sB, long long sC)
{
    int bx = blockIdx.x, by = blockIdx.y, bz = blockIdx.z;
    if (CSKIP && bx > by) return;
    const short* Ab = A + (long long)bz * sA + (long long)by * 128 * lda;
    const short* Bb = B + (long long)bz * sB + (long long)bx * 128 * ldb;
    __shared__ short lA[128 * 64];
    __shared__ short lB[128 * 64];
    int tid = threadIdx.x;
    int lane = tid & 63, wv = tid >> 6;
    int Kend = K;
    if (CK) { int kl = (by + 1) * 128; Kend = kl < K ? kl : K; }
    f32x4 acc[4][4];
#pragma unroll
    for (int i = 0; i < 4; i++)
#pragma unroll
        for (int j = 0; j < 4; j++)
#pragma unroll
            for (int r = 0; r < 4; r++) acc[i][j][r] = 0.0f;

    int rbase = (wv >> 1) * 64, cbase = (wv & 1) * 64;

    for (int k0 = 0; k0 < Kend; k0 += 64) {
        __syncthreads();
#pragma unroll
        for (int i = 0; i < 4; i++) {
            int ci  = i * 256 + tid;
            int row = ci >> 3;
            int kcG = (ci & 7) ^ (row & 7);        // XOR swizzle
            const short* gp = Ab + (long long)row * lda + k0 + kcG * 8;
            __builtin_amdgcn_global_load_lds((gmem_void*)gp, (lds_void*)(lA + ci * 8), 16, 0, 0);
        }
#pragma unroll
        for (int i = 0; i < 4; i++) {
            int ci  = i * 256 + tid;
            int row = ci >> 3;
            int kcG = (ci & 7) ^ (row & 7);
            const short* gp = Bb + (long long)row * ldb + k0 + kcG * 8;
            __builtin_amdgcn_global_load_lds((gmem_void*)gp, (lds_void*)(lB + ci * 8), 16, 0, 0);
        }
        __syncthreads();
#pragma unroll
        for (int kk = 0; kk < 2; kk++) {
            int kc = kk * 4 + (lane >> 4);          // k-chunk for this quad
            bf16x8 a[4], b[4];
#pragma unroll
            for (int t = 0; t < 4; t++) {
                int r = rbase + t * 16 + (lane & 15);
                a[t] = *(const bf16x8*)(lA + (r * 8 + (kc ^ (r & 7))) * 8);
            }
#pragma unroll
            for (int t = 0; t < 4; t++) {
                int r = cbase + t * 16 + (lane & 15);
                b[t] = *(const bf16x8*)(lB + (r * 8 + (kc ^ (r & 7))) * 8);
            }
#pragma unroll
            for (int mt = 0; mt < 4; mt++)
#pragma unroll
                for (int nt = 0; nt < 4; nt++)
                    acc[mt][nt] = __builtin_amdgcn_mfma_f32_16x16x32_bf16(a[mt], b[nt], acc[mt][nt], 0, 0, 0);
        }
    }

    int rq = (lane >> 4) * 4, cq = lane & 15;
#pragma unroll
    for (int mt = 0; mt < 4; mt++) {
#pragma unroll
        for (int nt = 0; nt < 4; nt++) {
#pragma unroll
            for (int r = 0; r < 4; r++) {
                int row = by * 128 + rbase + mt * 16 + rq + r;
                int col = bx * 128 + cbase + nt * 16 + cq;
                float v = acc[mt][nt][r] * scale;
                if (OM == 0) {
                    float* Cp = (float*)C + (long long)bz * sC;
                    Cp[(long long)row * ldc + col] = v;
                } else if (OM == 1) {
                    short* Cp = (short*)C + (long long)bz * sC;
                    Cp[(long long)row * ldc + col] = f2bf(v);
                } else {
                    short* Cp = (short*)C + (long long)bz * sC;
                    Cp[(long long)col * ldc + row] = f2bf(v);
                }
            }
        }
    }
}

// ---------------------------------------------------------------- RoPE
// reads fp32 qkv [s][6144] (q cols 0..2047, k cols 2048..4095)
__global__ __launch_bounds__(256) void rope_kernel(
    const float* __restrict__ qkv,
    short* __restrict__ qr, short* __restrict__ kr)
{
    int idx = blockIdx.x * 256 + threadIdx.x;      // 2048*16*64 = 2M
    int d = idx & 63;
    int h = (idx >> 6) & 15;
    int s = idx >> 10;
    float inv = exp2f((float)d * -0.20762050593261719f); // 10000^(-d/64)
    float ang = (float)s * inv;
    float sn, c;
    sincosf(ang, &sn, &c);
    long long io = (long long)s * 6144 + h * 128 + d;
    long long oo = (long long)h * 262144 + (long long)s * 128 + d;
    float x1 = qkv[io], x2 = qkv[io + 64];
    qr[oo]      = f2bf(x1 * c - x2 * sn);
    qr[oo + 64] = f2bf(x1 * sn + x2 * c);
    x1 = qkv[io + 2048]; x2 = qkv[io + 2112];
    kr[oo]      = f2bf(x1 * c - x2 * sn);
    kr[oo + 64] = f2bf(x1 * sn + x2 * c);
}

// ---------------------------------------------------------------- V transpose
// v_t[o][t] = (bf16) qkv[t][4096+o]; 64x64 tiles via LDS
__global__ __launch_bounds__(256) void vtrans_kernel(
    const float* __restrict__ qkv, short* __restrict__ v_t)
{
    int ot = blockIdx.x, tt = blockIdx.y;
    __shared__ short lt[64][72];
    int tid = threadIdx.x;
    int tr = tid >> 4, tc = tid & 15;
#pragma unroll
    for (int i = 0; i < 4; i++) {
        int t = tr + i * 16;
        const float* gp = qkv + (long long)(tt * 64 + t) * 6144 + 4096 + ot * 64 + tc * 4;
        float4 v = *(const float4*)gp;
        lt[tc * 4 + 0][t] = f2bf(v.x);
        lt[tc * 4 + 1][t] = f2bf(v.y);
        lt[tc * 4 + 2][t] = f2bf(v.z);
        lt[tc * 4 + 3][t] = f2bf(v.w);
    }
    __syncthreads();
    int orr = tid >> 3, oc = tid & 7;
#pragma unroll
    for (int i = 0; i < 2; i++) {
        int o = orr + i * 32;
        bf16x8 val = *(const bf16x8*)(&lt[o][oc * 8]);
        *(bf16x8*)(v_t + (long long)(ot * 64 + o) * 2048 + tt * 64 + oc * 8) = val;
    }
}

// ---------------------------------------------------------------- flash attn
// grid (qt=16, h=16), 256 thr / 4 waves; wave owns 32 q-rows.
// Per jt (64-wide K/V tile): S=Q K^T (MFMA), scale+causal mask, online
// softmax (per-row state in-quad), P->LDS (bf16), O += P V^T (MFMA).
__global__ __launch_bounds__(256) void flash_kernel(
    const short* __restrict__ q_r, const short* __restrict__ k_r,
    const short* __restrict__ v_t, short* __restrict__ attn)
{
    const float SC = 0.08838834764831845f;
    int qt = blockIdx.x, h = blockIdx.y;
    int tid = threadIdx.x, lane = tid & 63, wv = tid >> 6;
    int quad = lane >> 4, lm = lane & 15;

    __shared__ short lKV[64 * 128];   // K [64t][128d] / V [128d][64t], XOR-swizzled
    __shared__ short lP[128 * 72];    // P [128q][72 t-padded]

    const short* qb = q_r + h * 262144 + (qt * 128 + wv * 32) * 128;
    const short* kb = k_r + h * 262144;
    const short* vb = v_t + h * 128 * 2048;

    // Q fragments in registers: rows wv*32+mt*16+lm, k = kc*32+quad*8
    bf16x8 aq[2][4];
#pragma unroll
    for (int mt = 0; mt < 2; mt++)
#pragma unroll
        for (int kc = 0; kc < 4; kc++)
            aq[mt][kc] = *(const bf16x8*)(qb + (mt * 16 + lm) * 128 + kc * 32 + quad * 8);

    f32x4 ao[2][8];
#pragma unroll
    for (int mt = 0; mt < 2; mt++)
#pragma unroll
        for (int nt = 0; nt < 8; nt++)
#pragma unroll
            for (int r = 0; r < 4; r++) ao[mt][nt][r] = 0.0f;
    float mrow[2][4], lrow[2][4];
#pragma unroll
    for (int mt = 0; mt < 2; mt++)
#pragma unroll
        for (int r = 0; r < 4; r++) { mrow[mt][r] = -1e30f; lrow[mt][r] = 0.0f; }

    int jmax = 2 * qt + 1;
    for (int jt = 0; jt <= jmax; jt++) {
        __syncthreads();
        // stage K tile: 64 t-rows x 16 chunks (8 bf16 each)
#pragma unroll
        for (int i = 0; i < 4; i++) {
            int ci = i * 256 + tid;
            int r = ci >> 4, cp = ci & 15;
            int c = (cp & 8) | ((cp & 7) ^ (r & 7));
            const short* gp = kb + (jt * 64 + r) * 128 + c * 8;
            __builtin_amdgcn_global_load_lds((gmem_void*)gp, (lds_void*)(lKV + ci * 8), 16, 0, 0);
        }
        __syncthreads();
        // S = Q K^T  (wave: 32q x 64t)
        f32x4 as[2][4];
#pragma unroll
        for (int mt = 0; mt < 2; mt++)
#pragma unroll
            for (int nt = 0; nt < 4; nt++)
#pragma unroll
                for (int r = 0; r < 4; r++) as[mt][nt][r] = 0.0f;
#pragma unroll
        for (int kc = 0; kc < 4; kc++) {
#pragma unroll
            for (int nt = 0; nt < 4; nt++) {
                int r = nt * 16 + lm;
                int c = kc * 4 + quad;
                int slot = (c & 8) | ((c & 7) ^ (r & 7));
                bf16x8 bk = *(const bf16x8*)(lKV + (r * 16 + slot) * 8);
#pragma unroll
                for (int mt = 0; mt < 2; mt++)
                    as[mt][nt] = __builtin_amdgcn_mfma_f32_16x16x32_bf16(aq[mt][kc], bk, as[mt][nt], 0, 0, 0);
            }
        }
        // scale + causal mask (only the <=2 diagonal tiles need masking)
        bool diag = (jt >= 2 * qt);
#pragma unroll
        for (int mt = 0; mt < 2; mt++)
#pragma unroll
            for (int nt = 0; nt < 4; nt++)
#pragma unroll
                for (int r = 0; r < 4; r++) {
                    float s = as[mt][nt][r] * SC;
                    if (diag) {
                        int qg = qt * 128 + wv * 32 + mt * 16 + quad * 4 + r;
                        int tg = jt * 64 + nt * 16 + lm;
                        if (tg > qg) s = -1e30f;
                    }
                    as[mt][nt][r] = s;
                }
        // online softmax; rows live in-quad (C-layout row = quad*4+reg)
#pragma unroll
        for (int mt = 0; mt < 2; mt++) {
#pragma unroll
            for (int r = 0; r < 4; r++) {
                float mx = fmaxf(fmaxf(as[mt][0][r], as[mt][1][r]),
                                 fmaxf(as[mt][2][r], as[mt][3][r]));
#pragma unroll
                for (int off = 1; off < 16; off <<= 1) mx = fmaxf(mx, __shfl_xor(mx, off));
                float mnew = fmaxf(mrow[mt][r], mx);
                float alpha = __expf(mrow[mt][r] - mnew);
                mrow[mt][r] = mnew;
                float psum = 0.0f;
#pragma unroll
                for (int nt = 0; nt < 4; nt++) {
                    float p = __expf(as[mt][nt][r] - mnew);
                    as[mt][nt][r] = p;
                    psum += p;
                }
#pragma unroll
                for (int off = 1; off < 16; off <<= 1) psum += __shfl_xor(psum, off);
                lrow[mt][r] = lrow[mt][r] * alpha + psum;
#pragma unroll
                for (int nt = 0; nt < 8; nt++) ao[mt][nt][r] *= alpha;
                int rowl = wv * 32 + mt * 16 + quad * 4 + r;
#pragma unroll
                for (int nt = 0; nt < 4; nt++)
                    lP[rowl * 72 + nt * 16 + lm] = f2bf(as[mt][nt][r]);
            }
        }
        __syncthreads();
        // stage V tile: 128 d-rows x 8 chunks (t)
#pragma unroll
        for (int i = 0; i < 4; i++) {
            int ci = i * 256 + tid;
            int r = ci >> 3, cp = ci & 7;
            int c = cp ^ (r & 7);
            const short* gp = vb + r * 2048 + jt * 64 + c * 8;
            __builtin_amdgcn_global_load_lds((gmem_void*)gp, (lds_void*)(lKV + ci * 8), 16, 0, 0);
        }
        __syncthreads();
        // O += P V^T
#pragma unroll
        for (int kt = 0; kt < 2; kt++) {
            bf16x8 ap[2];
#pragma unroll
            for (int mt = 0; mt < 2; mt++) {
                int m = wv * 32 + mt * 16 + lm;
                ap[mt] = *(const bf16x8*)(lP + m * 72 + kt * 32 + quad * 8);
            }
#pragma unroll
            for (int nt = 0; nt < 8; nt++) {
                int r = nt * 16 + lm;
                int c = kt * 4 + quad;
                int slot = c ^ (r & 7);
                bf16x8 bv = *(const bf16x8*)(lKV + (r * 8 + slot) * 8);
#pragma unroll
                for (int mt = 0; mt < 2; mt++)
                    ao[mt][nt] = __builtin_amdgcn_mfma_f32_16x16x32_bf16(ap[mt], bv, ao[mt][nt], 0, 0, 0);
            }
        }
    }
    // epilogue: O /= l, write attn bf16 [s][2048]
#pragma unroll
    for (int mt = 0; mt < 2; mt++)
#pragma unroll
        for (int r = 0; r < 4; r++) {
            float inv = 1.0f / lrow[mt][r];
            int sg = qt * 128 + wv * 32 + mt * 16 + quad * 4 + r;
#pragma unroll
            for (int nt = 0; nt < 8; nt++) {
                int dg = h * 128 + nt * 16 + lm;
                attn[(long long)sg * 2048 + dg] = f2bf(ao[mt][nt][r] * inv);
            }
        }
}

// ---------------------------------------------------------------- launch
extern "C" void kernel_launch(void* const* d_in, const int* in_sizes, int n_in,
                              void* d_out, int out_size, void* d_ws, size_t ws_size,
                              hipStream_t stream)
{
    const void* x  = d_in[0];
    const void* wq = d_in[2];
    const void* wk = d_in[3];
    const void* wv = d_in[4];
    const void* wo = d_in[5];

    char* ws = (char*)d_ws;
    size_t off = 0;
    auto alloc = [&](size_t b) { void* p = ws + off; off += (b + 255) & ~(size_t)255; return p; };
    short* wqkv_q = (short*)alloc(25165824);   // [6144][2048] bf16 (q,k,v)
    short* wo_q   = (short*)alloc(8388608);
    float* qkv    = (float*)alloc(50331648);   // [2048][6144] fp32
    short* v_t    = (short*)alloc(8388608);    // [o][t]
    short* q_r    = (short*)alloc(8388608);    // [h][s][128]
    short* k_r    = (short*)alloc(8388608);
    short* attn   = (short*)alloc(8388608);    // [s][2048]
    short* x_bf   = (short*)alloc(8388608);
    int*   flag   = (int*)alloc(256);
    if (off > ws_size) return;                 // ~127 MB

    zero_flag<<<1, 64, 0, stream>>>(flag);
    detect_kernel<<<256, 256, 0, stream>>>(
        (const unsigned short*)x, in_sizes[0], flag);
    convert_kernel<<<16384, 256, 0, stream>>>(x, x_bf, 4194304, flag);

    quant_kernel<<<32768, 256, 0, stream>>>(wq, wk, wv, wo,
        wqkv_q, wqkv_q + 4194304, wqkv_q + 8388608, wo_q, flag);

    // QKV fused projection: [2048][6144] fp32
    gemm_bt<0,false,false><<<dim3(48,16,1), 256, 0, stream>>>(
        x_bf, wqkv_q, qkv, 2048,6144,2048, 2048,2048,6144, 1.0f, 0,0,0);

    rope_kernel<<<8192, 256, 0, stream>>>(qkv, q_r, k_r);
    vtrans_kernel<<<dim3(32,32), 256, 0, stream>>>(qkv, v_t);

    flash_kernel<<<dim3(16,16), 256, 0, stream>>>(q_r, k_r, v_t, attn);

    gemm_bt<0,false,false><<<dim3(16,16,1), 256, 0, stream>>>(
        attn, wo_q, d_out, 2048,2048,2048, 2048,2048,2048, 1.0f, 0,0,0);
}

// Round 6
// 361.929 us; speedup vs baseline: 1.2675x; 1.0554x over previous
//
#include <hip/hip_runtime.h>
#include <cstdint>
#include <cstddef>

// BitLlamaAttention: B=1, S=2048, HIDDEN=2048, NH=16, HD=128, GROUP=128
// Inputs fp32, output fp32. r5 passed @382us; flash_kernel was 119us with
// 6% occupancy (256 blocks, causal skew) -> r6 rebuilds flash:
//   - 64-row Q tiles, grid(32,16)=512 blocks, longest-first (qt=31-bx)
//   - split lK/lV buffers, software-pipelined staging (V overlaps QK+softmax,
//     next K overlaps PV)
//   - lP 16-col-group XOR swizzle by (row>>2)&3 kills 4-way quad conflicts
// Everything else identical to r5 (verified).

typedef __attribute__((ext_vector_type(8))) short bf16x8;
typedef __attribute__((ext_vector_type(4))) float f32x4;
typedef __attribute__((address_space(3))) void lds_void;
typedef const __attribute__((address_space(1))) void gmem_void;

__device__ __forceinline__ short f2bf(float x) {
    union { float f; uint32_t u; } c; c.f = x;
    uint32_t r = (c.u + 0x7FFFu + ((c.u >> 16) & 1u)) >> 16;
    return (short)r;
}
__device__ __forceinline__ float bf2f(short x) {
    union { uint32_t u; float f; } c; c.u = ((uint32_t)(uint16_t)x) << 16;
    return c.f;
}

// ------------------------------------------------------------ dtype probe
__global__ __launch_bounds__(64) void zero_flag(int* f) {
    if (threadIdx.x == 0) *f = 0;
}

__global__ __launch_bounds__(256) void detect_kernel(
    const unsigned short* __restrict__ p, int n, int* __restrict__ flag)
{
    int tid = blockIdx.x * 256 + threadIdx.x;
    int cnt = 0;
    for (int i = tid; i < n; i += 65536) {
        int e = (p[i] >> 7) & 0xFF;
        cnt += (e >= 0xF0) ? 1 : 0;
    }
#pragma unroll
    for (int off = 1; off < 64; off <<= 1) cnt += __shfl_xor(cnt, off);
    if ((threadIdx.x & 63) == 0 && cnt) atomicAdd(flag, cnt);
}

__global__ __launch_bounds__(256) void convert_kernel(
    const void* __restrict__ in, short* __restrict__ out, int n,
    const int* __restrict__ flag)
{
    bool isf32 = (*flag > 1000);
    int i = blockIdx.x * 256 + threadIdx.x;
    if (i >= n) return;
    out[i] = isf32 ? f2bf(((const float*)in)[i]) : ((const short*)in)[i];
}

// ---------------------------------------------------------------- quantize
__global__ __launch_bounds__(256) void quant_kernel(
    const void* __restrict__ w0, const void* __restrict__ w1,
    const void* __restrict__ w2, const void* __restrict__ w3,
    short* __restrict__ q0, short* __restrict__ q1,
    short* __restrict__ q2, short* __restrict__ q3,
    const int* __restrict__ flag)
{
    bool isf32 = (*flag > 1000);
    int gw   = blockIdx.x * 4 + (threadIdx.x >> 6);
    int lane = threadIdx.x & 63;
    int mat  = gw >> 15;
    int g    = gw & 32767;
    const void* w = (mat == 0) ? w0 : (mat == 1) ? w1 : (mat == 2) ? w2 : w3;
    short*      q = (mat == 0) ? q0 : (mat == 1) ? q1 : (mat == 2) ? q2 : q3;
    int idx = g * 64 + lane;                       // index of element PAIR
    float a, b;
    if (isf32) {
        const float* wf = (const float*)w;
        a = wf[idx * 2]; b = wf[idx * 2 + 1];
    } else {
        int pr = ((const int*)w)[idx];
        a = bf2f((short)(pr & 0xFFFF));
        b = bf2f((short)(((uint32_t)pr) >> 16));
    }
    float s = fabsf(a) + fabsf(b);
#pragma unroll
    for (int off = 1; off < 64; off <<= 1) s += __shfl_xor(s, off);
    float scale = fmaxf(s * (1.0f / 128.0f), 1e-8f);
    float na = a / scale, nb = b / scale;
    float ra = (na > 0.5f) ? scale : (na < -0.5f) ? -scale : 0.0f;
    float rb = (nb > 0.5f) ? scale : (nb < -0.5f) ? -scale : 0.0f;
    ((int*)q)[idx] = (int)(uint16_t)f2bf(ra) | ((int)(uint16_t)f2bf(rb) << 16);
}

// ---------------------------------------------------------------- GEMM (B^T)
template<int OM, bool CSKIP, bool CK>
__global__ __launch_bounds__(256) void gemm_bt(
    const short* __restrict__ A, const short* __restrict__ B, void* __restrict__ C,
    int M, int N, int K, int lda, int ldb, int ldc, float scale,
    long long sA, long long sB, long long sC)
{
    int bx = blockIdx.x, by = blockIdx.y, bz = blockIdx.z;
    if (CSKIP && bx > by) return;
    const short* Ab = A + (long long)bz * sA + (long long)by * 128 * lda;
    const short* Bb = B + (long long)bz * sB + (long long)bx * 128 * ldb;
    __shared__ short lA[128 * 64];
    __shared__ short lB[128 * 64];
    int tid = threadIdx.x;
    int lane = tid & 63, wv = tid >> 6;
    int Kend = K;
    if (CK) { int kl = (by + 1) * 128; Kend = kl < K ? kl : K; }
    f32x4 acc[4][4];
#pragma unroll
    for (int i = 0; i < 4; i++)
#pragma unroll
        for (int j = 0; j < 4; j++)
#pragma unroll
            for (int r = 0; r < 4; r++) acc[i][j][r] = 0.0f;

    int rbase = (wv >> 1) * 64, cbase = (wv & 1) * 64;

    for (int k0 = 0; k0 < Kend; k0 += 64) {
        __syncthreads();
#pragma unroll
        for (int i = 0; i < 4; i++) {
            int ci  = i * 256 + tid;
            int row = ci >> 3;
            int kcG = (ci & 7) ^ (row & 7);        // XOR swizzle
            const short* gp = Ab + (long long)row * lda + k0 + kcG * 8;
            __builtin_amdgcn_global_load_lds((gmem_void*)gp, (lds_void*)(lA + ci * 8), 16, 0, 0);
        }
#pragma unroll
        for (int i = 0; i < 4; i++) {
            int ci  = i * 256 + tid;
            int row = ci >> 3;
            int kcG = (ci & 7) ^ (row & 7);
            const short* gp = Bb + (long long)row * ldb + k0 + kcG * 8;
            __builtin_amdgcn_global_load_lds((gmem_void*)gp, (lds_void*)(lB + ci * 8), 16, 0, 0);
        }
        __syncthreads();
#pragma unroll
        for (int kk = 0; kk < 2; kk++) {
            int kc = kk * 4 + (lane >> 4);          // k-chunk for this quad
            bf16x8 a[4], b[4];
#pragma unroll
            for (int t = 0; t < 4; t++) {
                int r = rbase + t * 16 + (lane & 15);
                a[t] = *(const bf16x8*)(lA + (r * 8 + (kc ^ (r & 7))) * 8);
            }
#pragma unroll
            for (int t = 0; t < 4; t++) {
                int r = cbase + t * 16 + (lane & 15);
                b[t] = *(const bf16x8*)(lB + (r * 8 + (kc ^ (r & 7))) * 8);
            }
#pragma unroll
            for (int mt = 0; mt < 4; mt++)
#pragma unroll
                for (int nt = 0; nt < 4; nt++)
                    acc[mt][nt] = __builtin_amdgcn_mfma_f32_16x16x32_bf16(a[mt], b[nt], acc[mt][nt], 0, 0, 0);
        }
    }

    int rq = (lane >> 4) * 4, cq = lane & 15;
#pragma unroll
    for (int mt = 0; mt < 4; mt++) {
#pragma unroll
        for (int nt = 0; nt < 4; nt++) {
#pragma unroll
            for (int r = 0; r < 4; r++) {
                int row = by * 128 + rbase + mt * 16 + rq + r;
                int col = bx * 128 + cbase + nt * 16 + cq;
                float v = acc[mt][nt][r] * scale;
                if (OM == 0) {
                    float* Cp = (float*)C + (long long)bz * sC;
                    Cp[(long long)row * ldc + col] = v;
                } else if (OM == 1) {
                    short* Cp = (short*)C + (long long)bz * sC;
                    Cp[(long long)row * ldc + col] = f2bf(v);
                } else {
                    short* Cp = (short*)C + (long long)bz * sC;
                    Cp[(long long)col * ldc + row] = f2bf(v);
                }
            }
        }
    }
}

// ---------------------------------------------------------------- RoPE
__global__ __launch_bounds__(256) void rope_kernel(
    const float* __restrict__ qkv,
    short* __restrict__ qr, short* __restrict__ kr)
{
    int idx = blockIdx.x * 256 + threadIdx.x;      // 2048*16*64 = 2M
    int d = idx & 63;
    int h = (idx >> 6) & 15;
    int s = idx >> 10;
    float inv = exp2f((float)d * -0.20762050593261719f); // 10000^(-d/64)
    float ang = (float)s * inv;
    float sn, c;
    sincosf(ang, &sn, &c);
    long long io = (long long)s * 6144 + h * 128 + d;
    long long oo = (long long)h * 262144 + (long long)s * 128 + d;
    float x1 = qkv[io], x2 = qkv[io + 64];
    qr[oo]      = f2bf(x1 * c - x2 * sn);
    qr[oo + 64] = f2bf(x1 * sn + x2 * c);
    x1 = qkv[io + 2048]; x2 = qkv[io + 2112];
    kr[oo]      = f2bf(x1 * c - x2 * sn);
    kr[oo + 64] = f2bf(x1 * sn + x2 * c);
}

// ---------------------------------------------------------------- V transpose
__global__ __launch_bounds__(256) void vtrans_kernel(
    const float* __restrict__ qkv, short* __restrict__ v_t)
{
    int ot = blockIdx.x, tt = blockIdx.y;
    __shared__ short lt[64][72];
    int tid = threadIdx.x;
    int tr = tid >> 4, tc = tid & 15;
#pragma unroll
    for (int i = 0; i < 4; i++) {
        int t = tr + i * 16;
        const float* gp = qkv + (long long)(tt * 64 + t) * 6144 + 4096 + ot * 64 + tc * 4;
        float4 v = *(const float4*)gp;
        lt[tc * 4 + 0][t] = f2bf(v.x);
        lt[tc * 4 + 1][t] = f2bf(v.y);
        lt[tc * 4 + 2][t] = f2bf(v.z);
        lt[tc * 4 + 3][t] = f2bf(v.w);
    }
    __syncthreads();
    int orr = tid >> 3, oc = tid & 7;
#pragma unroll
    for (int i = 0; i < 2; i++) {
        int o = orr + i * 32;
        bf16x8 val = *(const bf16x8*)(&lt[o][oc * 8]);
        *(bf16x8*)(v_t + (long long)(ot * 64 + o) * 2048 + tt * 64 + oc * 8) = val;
    }
}

// ---------------------------------------------------------------- flash attn
// grid (32 qt-tiles, 16 h), 256 thr / 4 waves; wave owns 16 q-rows of a
// 64-row Q tile. qt = 31-bx (longest blocks dispatch first). Pipelined:
// issue V_jt; S=QK^T; softmax->lP; barrier; issue K_{jt+1}; O+=PV; barrier.
__global__ __launch_bounds__(256) void flash_kernel(
    const short* __restrict__ q_r, const short* __restrict__ k_r,
    const short* __restrict__ v_t, short* __restrict__ attn)
{
    const float SC = 0.08838834764831845f;
    int qt = 31 - blockIdx.x;
    int h = blockIdx.y;
    int tid = threadIdx.x, lane = tid & 63, wv = tid >> 6;
    int quad = lane >> 4, lm = lane & 15;

    __shared__ short lK[64 * 128];    // K [64t][128d], chunk-swizzled
    __shared__ short lV[128 * 64];    // V [128d][64t], chunk-swizzled
    __shared__ short lP[64 * 72];     // P [64q][64t], 16-col groups swizzled

    const short* qb = q_r + h * 262144 + (qt * 64 + wv * 16) * 128;
    const short* kb = k_r + h * 262144;
    const short* vb = v_t + h * 128 * 2048;

    // Q fragments: rows lm (of wave's 16), k = kc*32+quad*8
    bf16x8 aq[4];
#pragma unroll
    for (int kc = 0; kc < 4; kc++)
        aq[kc] = *(const bf16x8*)(qb + lm * 128 + kc * 32 + quad * 8);

    f32x4 ao[8];
#pragma unroll
    for (int nt = 0; nt < 8; nt++)
#pragma unroll
        for (int r = 0; r < 4; r++) ao[nt][r] = 0.0f;
    float mrow[4], lrow[4];
#pragma unroll
    for (int r = 0; r < 4; r++) { mrow[r] = -1e30f; lrow[r] = 0.0f; }

    // prologue: stage K_0
#pragma unroll
    for (int i = 0; i < 4; i++) {
        int ci = i * 256 + tid;
        int r = ci >> 4, cp = ci & 15;
        int c = (cp & 8) | ((cp & 7) ^ (r & 7));
        const short* gp = kb + r * 128 + c * 8;
        __builtin_amdgcn_global_load_lds((gmem_void*)gp, (lds_void*)(lK + ci * 8), 16, 0, 0);
    }
    __syncthreads();

    for (int jt = 0; jt <= qt; jt++) {
        // 1. issue V_jt (consumed after next barrier)
#pragma unroll
        for (int i = 0; i < 4; i++) {
            int ci = i * 256 + tid;
            int r = ci >> 3, cp = ci & 7;
            int c = cp ^ (r & 7);
            const short* gp = vb + r * 2048 + jt * 64 + c * 8;
            __builtin_amdgcn_global_load_lds((gmem_void*)gp, (lds_void*)(lV + ci * 8), 16, 0, 0);
        }
        // 2. S = Q K^T  (wave: 16q x 64t)
        f32x4 as[4];
#pragma unroll
        for (int nt = 0; nt < 4; nt++)
#pragma unroll
            for (int r = 0; r < 4; r++) as[nt][r] = 0.0f;
#pragma unroll
        for (int kc = 0; kc < 4; kc++) {
#pragma unroll
            for (int nt = 0; nt < 4; nt++) {
                int r = nt * 16 + lm;
                int c = kc * 4 + quad;
                int slot = (c & 8) | ((c & 7) ^ (r & 7));
                bf16x8 bk = *(const bf16x8*)(lK + (r * 16 + slot) * 8);
                as[nt] = __builtin_amdgcn_mfma_f32_16x16x32_bf16(aq[kc], bk, as[nt], 0, 0, 0);
            }
        }
        // 3. scale + mask (diag tile only) + online softmax + P->lP
        bool diag = (jt == qt);
#pragma unroll
        for (int nt = 0; nt < 4; nt++)
#pragma unroll
            for (int r = 0; r < 4; r++) {
                float s = as[nt][r] * SC;
                if (diag) {
                    int qg = wv * 16 + quad * 4 + r;          // within tile
                    int tg = nt * 16 + lm;
                    if (tg > qg) s = -1e30f;
                }
                as[nt][r] = s;
            }
#pragma unroll
        for (int r = 0; r < 4; r++) {
            float mx = fmaxf(fmaxf(as[0][r], as[1][r]), fmaxf(as[2][r], as[3][r]));
#pragma unroll
            for (int off = 1; off < 16; off <<= 1) mx = fmaxf(mx, __shfl_xor(mx, off));
            float mnew = fmaxf(mrow[r], mx);
            float alpha = __expf(mrow[r] - mnew);
            mrow[r] = mnew;
            float psum = 0.0f;
#pragma unroll
            for (int nt = 0; nt < 4; nt++) {
                float p = __expf(as[nt][r] - mnew);
                as[nt][r] = p;
                psum += p;
            }
#pragma unroll
            for (int off = 1; off < 16; off <<= 1) psum += __shfl_xor(psum, off);
            lrow[r] = lrow[r] * alpha + psum;
#pragma unroll
            for (int nt = 0; nt < 8; nt++) ao[nt][r] *= alpha;
            int row = wv * 16 + quad * 4 + r;
            int sw = (row >> 2) & 3;
#pragma unroll
            for (int nt = 0; nt < 4; nt++)
                lP[row * 72 + ((nt ^ sw) * 16) + lm] = f2bf(as[nt][r]);
        }
        // 4. barrier: V arrived, lP visible, lK free
        __syncthreads();
        // 5. issue K_{jt+1}
        if (jt < qt) {
#pragma unroll
            for (int i = 0; i < 4; i++) {
                int ci = i * 256 + tid;
                int r = ci >> 4, cp = ci & 15;
                int c = (cp & 8) | ((cp & 7) ^ (r & 7));
                const short* gp = kb + ((jt + 1) * 64 + r) * 128 + c * 8;
                __builtin_amdgcn_global_load_lds((gmem_void*)gp, (lds_void*)(lK + ci * 8), 16, 0, 0);
            }
        }
        // 6. O += P V^T
#pragma unroll
        for (int kt = 0; kt < 2; kt++) {
            int prow = wv * 16 + lm;
            int sw = (lm >> 2) & 3;
            int g = kt * 2 + (quad >> 1);
            bf16x8 ap = *(const bf16x8*)(lP + prow * 72 + ((g ^ sw) * 16) + (quad & 1) * 8);
#pragma unroll
            for (int nt = 0; nt < 8; nt++) {
                int r = nt * 16 + lm;
                int c = kt * 4 + quad;
                int slot = c ^ (r & 7);
                bf16x8 bv = *(const bf16x8*)(lV + (r * 8 + slot) * 8);
                ao[nt] = __builtin_amdgcn_mfma_f32_16x16x32_bf16(ap, bv, ao[nt], 0, 0, 0);
            }
        }
        // 7. barrier: K_{jt+1} arrived, lV/lP free
        __syncthreads();
    }
    // epilogue
#pragma unroll
    for (int r = 0; r < 4; r++) {
        float inv = 1.0f / lrow[r];
        int sg = qt * 64 + wv * 16 + quad * 4 + r;
#pragma unroll
        for (int nt = 0; nt < 8; nt++) {
            int dg = h * 128 + nt * 16 + lm;
            attn[(long long)sg * 2048 + dg] = f2bf(ao[nt][r] * inv);
        }
    }
}

// ---------------------------------------------------------------- launch
extern "C" void kernel_launch(void* const* d_in, const int* in_sizes, int n_in,
                              void* d_out, int out_size, void* d_ws, size_t ws_size,
                              hipStream_t stream)
{
    const void* x  = d_in[0];
    const void* wq = d_in[2];
    const void* wk = d_in[3];
    const void* wv = d_in[4];
    const void* wo = d_in[5];

    char* ws = (char*)d_ws;
    size_t off = 0;
    auto alloc = [&](size_t b) { void* p = ws + off; off += (b + 255) & ~(size_t)255; return p; };
    short* wqkv_q = (short*)alloc(25165824);   // [6144][2048] bf16 (q,k,v)
    short* wo_q   = (short*)alloc(8388608);
    float* qkv    = (float*)alloc(50331648);   // [2048][6144] fp32
    short* v_t    = (short*)alloc(8388608);    // [o][t]
    short* q_r    = (short*)alloc(8388608);    // [h][s][128]
    short* k_r    = (short*)alloc(8388608);
    short* attn   = (short*)alloc(8388608);    // [s][2048]
    short* x_bf   = (short*)alloc(8388608);
    int*   flag   = (int*)alloc(256);
    if (off > ws_size) return;                 // ~127 MB

    zero_flag<<<1, 64, 0, stream>>>(flag);
    detect_kernel<<<256, 256, 0, stream>>>(
        (const unsigned short*)x, in_sizes[0], flag);
    convert_kernel<<<16384, 256, 0, stream>>>(x, x_bf, 4194304, flag);

    quant_kernel<<<32768, 256, 0, stream>>>(wq, wk, wv, wo,
        wqkv_q, wqkv_q + 4194304, wqkv_q + 8388608, wo_q, flag);

    // QKV fused projection: [2048][6144] fp32
    gemm_bt<0,false,false><<<dim3(48,16,1), 256, 0, stream>>>(
        x_bf, wqkv_q, qkv, 2048,6144,2048, 2048,2048,6144, 1.0f, 0,0,0);

    rope_kernel<<<8192, 256, 0, stream>>>(qkv, q_r, k_r);
    vtrans_kernel<<<dim3(32,32), 256, 0, stream>>>(qkv, v_t);

    flash_kernel<<<dim3(32,16), 256, 0, stream>>>(q_r, k_r, v_t, attn);

    gemm_bt<0,false,false><<<dim3(16,16,1), 256, 0, stream>>>(
        attn, wo_q, d_out, 2048,2048,2048, 2048,2048,2048, 1.0f, 0,0,0);
}

// Round 7
// 334.100 us; speedup vs baseline: 1.3731x; 1.0833x over previous
//
#include <hip/hip_runtime.h>
#include <cstdint>
#include <cstddef>

// BitLlamaAttention: B=1, S=2048, HIDDEN=2048, NH=16, HD=128, GROUP=128
// Inputs fp32, output fp32. r6 @362us; flash 93us, latency/occupancy-bound
// (6.8k cyc/block-iter vs 310 cyc MFMA; 2 blocks/CU; avg occupancy 10.7%).
// r7 flash changes:
//   - LDS 41984 -> 40960 B (lP 64x64, slot-rotation swizzle (g+row)&7:
//     writes <=2-way, PV b128 reads exactly 2-way = free) => 4 blocks/CU
//   - split-j: 1024 blocks (qt,h,z), z halves the j-range; unnormalized
//     fp32 O-partials + (m,l); combine_kernel merges => full balance + no tail
//   - static longest-first dispatch (qt = 31-(bid>>5))
// Everything else identical to r6 (verified).

typedef __attribute__((ext_vector_type(8))) short bf16x8;
typedef __attribute__((ext_vector_type(4))) float f32x4;
typedef __attribute__((address_space(3))) void lds_void;
typedef const __attribute__((address_space(1))) void gmem_void;

__device__ __forceinline__ short f2bf(float x) {
    union { float f; uint32_t u; } c; c.f = x;
    uint32_t r = (c.u + 0x7FFFu + ((c.u >> 16) & 1u)) >> 16;
    return (short)r;
}
__device__ __forceinline__ float bf2f(short x) {
    union { uint32_t u; float f; } c; c.u = ((uint32_t)(uint16_t)x) << 16;
    return c.f;
}

// ------------------------------------------------------------ dtype probe
__global__ __launch_bounds__(64) void zero_flag(int* f) {
    if (threadIdx.x == 0) *f = 0;
}

__global__ __launch_bounds__(256) void detect_kernel(
    const unsigned short* __restrict__ p, int n, int* __restrict__ flag)
{
    int tid = blockIdx.x * 256 + threadIdx.x;
    int cnt = 0;
    for (int i = tid; i < n; i += 65536) {
        int e = (p[i] >> 7) & 0xFF;
        cnt += (e >= 0xF0) ? 1 : 0;
    }
#pragma unroll
    for (int off = 1; off < 64; off <<= 1) cnt += __shfl_xor(cnt, off);
    if ((threadIdx.x & 63) == 0 && cnt) atomicAdd(flag, cnt);
}

__global__ __launch_bounds__(256) void convert_kernel(
    const void* __restrict__ in, short* __restrict__ out, int n,
    const int* __restrict__ flag)
{
    bool isf32 = (*flag > 1000);
    int i = blockIdx.x * 256 + threadIdx.x;
    if (i >= n) return;
    out[i] = isf32 ? f2bf(((const float*)in)[i]) : ((const short*)in)[i];
}

// ---------------------------------------------------------------- quantize
__global__ __launch_bounds__(256) void quant_kernel(
    const void* __restrict__ w0, const void* __restrict__ w1,
    const void* __restrict__ w2, const void* __restrict__ w3,
    short* __restrict__ q0, short* __restrict__ q1,
    short* __restrict__ q2, short* __restrict__ q3,
    const int* __restrict__ flag)
{
    bool isf32 = (*flag > 1000);
    int gw   = blockIdx.x * 4 + (threadIdx.x >> 6);
    int lane = threadIdx.x & 63;
    int mat  = gw >> 15;
    int g    = gw & 32767;
    const void* w = (mat == 0) ? w0 : (mat == 1) ? w1 : (mat == 2) ? w2 : w3;
    short*      q = (mat == 0) ? q0 : (mat == 1) ? q1 : (mat == 2) ? q2 : q3;
    int idx = g * 64 + lane;                       // index of element PAIR
    float a, b;
    if (isf32) {
        const float* wf = (const float*)w;
        a = wf[idx * 2]; b = wf[idx * 2 + 1];
    } else {
        int pr = ((const int*)w)[idx];
        a = bf2f((short)(pr & 0xFFFF));
        b = bf2f((short)(((uint32_t)pr) >> 16));
    }
    float s = fabsf(a) + fabsf(b);
#pragma unroll
    for (int off = 1; off < 64; off <<= 1) s += __shfl_xor(s, off);
    float scale = fmaxf(s * (1.0f / 128.0f), 1e-8f);
    float na = a / scale, nb = b / scale;
    float ra = (na > 0.5f) ? scale : (na < -0.5f) ? -scale : 0.0f;
    float rb = (nb > 0.5f) ? scale : (nb < -0.5f) ? -scale : 0.0f;
    ((int*)q)[idx] = (int)(uint16_t)f2bf(ra) | ((int)(uint16_t)f2bf(rb) << 16);
}

// ---------------------------------------------------------------- GEMM (B^T)
template<int OM, bool CSKIP, bool CK>
__global__ __launch_bounds__(256) void gemm_bt(
    const short* __restrict__ A, const short* __restrict__ B, void* __restrict__ C,
    int M, int N, int K, int lda, int ldb, int ldc, float scale,
    long long sA, long long sB, long long sC)
{
    int bx = blockIdx.x, by = blockIdx.y, bz = blockIdx.z;
    if (CSKIP && bx > by) return;
    const short* Ab = A + (long long)bz * sA + (long long)by * 128 * lda;
    const short* Bb = B + (long long)bz * sB + (long long)bx * 128 * ldb;
    __shared__ short lA[128 * 64];
    __shared__ short lB[128 * 64];
    int tid = threadIdx.x;
    int lane = tid & 63, wv = tid >> 6;
    int Kend = K;
    if (CK) { int kl = (by + 1) * 128; Kend = kl < K ? kl : K; }
    f32x4 acc[4][4];
#pragma unroll
    for (int i = 0; i < 4; i++)
#pragma unroll
        for (int j = 0; j < 4; j++)
#pragma unroll
            for (int r = 0; r < 4; r++) acc[i][j][r] = 0.0f;

    int rbase = (wv >> 1) * 64, cbase = (wv & 1) * 64;

    for (int k0 = 0; k0 < Kend; k0 += 64) {
        __syncthreads();
#pragma unroll
        for (int i = 0; i < 4; i++) {
            int ci  = i * 256 + tid;
            int row = ci >> 3;
            int kcG = (ci & 7) ^ (row & 7);        // XOR swizzle
            const short* gp = Ab + (long long)row * lda + k0 + kcG * 8;
            __builtin_amdgcn_global_load_lds((gmem_void*)gp, (lds_void*)(lA + ci * 8), 16, 0, 0);
        }
#pragma unroll
        for (int i = 0; i < 4; i++) {
            int ci  = i * 256 + tid;
            int row = ci >> 3;
            int kcG = (ci & 7) ^ (row & 7);
            const short* gp = Bb + (long long)row * ldb + k0 + kcG * 8;
            __builtin_amdgcn_global_load_lds((gmem_void*)gp, (lds_void*)(lB + ci * 8), 16, 0, 0);
        }
        __syncthreads();
#pragma unroll
        for (int kk = 0; kk < 2; kk++) {
            int kc = kk * 4 + (lane >> 4);          // k-chunk for this quad
            bf16x8 a[4], b[4];
#pragma unroll
            for (int t = 0; t < 4; t++) {
                int r = rbase + t * 16 + (lane & 15);
                a[t] = *(const bf16x8*)(lA + (r * 8 + (kc ^ (r & 7))) * 8);
            }
#pragma unroll
            for (int t = 0; t < 4; t++) {
                int r = cbase + t * 16 + (lane & 15);
                b[t] = *(const bf16x8*)(lB + (r * 8 + (kc ^ (r & 7))) * 8);
            }
#pragma unroll
            for (int mt = 0; mt < 4; mt++)
#pragma unroll
                for (int nt = 0; nt < 4; nt++)
                    acc[mt][nt] = __builtin_amdgcn_mfma_f32_16x16x32_bf16(a[mt], b[nt], acc[mt][nt], 0, 0, 0);
        }
    }

    int rq = (lane >> 4) * 4, cq = lane & 15;
#pragma unroll
    for (int mt = 0; mt < 4; mt++) {
#pragma unroll
        for (int nt = 0; nt < 4; nt++) {
#pragma unroll
            for (int r = 0; r < 4; r++) {
                int row = by * 128 + rbase + mt * 16 + rq + r;
                int col = bx * 128 + cbase + nt * 16 + cq;
                float v = acc[mt][nt][r] * scale;
                if (OM == 0) {
                    float* Cp = (float*)C + (long long)bz * sC;
                    Cp[(long long)row * ldc + col] = v;
                } else if (OM == 1) {
                    short* Cp = (short*)C + (long long)bz * sC;
                    Cp[(long long)row * ldc + col] = f2bf(v);
                } else {
                    short* Cp = (short*)C + (long long)bz * sC;
                    Cp[(long long)col * ldc + row] = f2bf(v);
                }
            }
        }
    }
}

// ---------------------------------------------------------------- RoPE
__global__ __launch_bounds__(256) void rope_kernel(
    const float* __restrict__ qkv,
    short* __restrict__ qr, short* __restrict__ kr)
{
    int idx = blockIdx.x * 256 + threadIdx.x;      // 2048*16*64 = 2M
    int d = idx & 63;
    int h = (idx >> 6) & 15;
    int s = idx >> 10;
    float inv = exp2f((float)d * -0.20762050593261719f); // 10000^(-d/64)
    float ang = (float)s * inv;
    float sn, c;
    sincosf(ang, &sn, &c);
    long long io = (long long)s * 6144 + h * 128 + d;
    long long oo = (long long)h * 262144 + (long long)s * 128 + d;
    float x1 = qkv[io], x2 = qkv[io + 64];
    qr[oo]      = f2bf(x1 * c - x2 * sn);
    qr[oo + 64] = f2bf(x1 * sn + x2 * c);
    x1 = qkv[io + 2048]; x2 = qkv[io + 2112];
    kr[oo]      = f2bf(x1 * c - x2 * sn);
    kr[oo + 64] = f2bf(x1 * sn + x2 * c);
}

// ---------------------------------------------------------------- V transpose
__global__ __launch_bounds__(256) void vtrans_kernel(
    const float* __restrict__ qkv, short* __restrict__ v_t)
{
    int ot = blockIdx.x, tt = blockIdx.y;
    __shared__ short lt[64][72];
    int tid = threadIdx.x;
    int tr = tid >> 4, tc = tid & 15;
#pragma unroll
    for (int i = 0; i < 4; i++) {
        int t = tr + i * 16;
        const float* gp = qkv + (long long)(tt * 64 + t) * 6144 + 4096 + ot * 64 + tc * 4;
        float4 v = *(const float4*)gp;
        lt[tc * 4 + 0][t] = f2bf(v.x);
        lt[tc * 4 + 1][t] = f2bf(v.y);
        lt[tc * 4 + 2][t] = f2bf(v.z);
        lt[tc * 4 + 3][t] = f2bf(v.w);
    }
    __syncthreads();
    int orr = tid >> 3, oc = tid & 7;
#pragma unroll
    for (int i = 0; i < 2; i++) {
        int o = orr + i * 32;
        bf16x8 val = *(const bf16x8*)(&lt[o][oc * 8]);
        *(bf16x8*)(v_t + (long long)(ot * 64 + o) * 2048 + tt * 64 + oc * 8) = val;
    }
}

// ---------------------------------------------------------------- flash attn
// 1024 blocks: bid -> qt = 31-(bid>>5) (longest first), h = (bid>>1)&15,
// z = bid&1 (j-range half). 4 waves x 16 q-rows. Writes unnormalized fp32
// O-partial + per-row (m,l). LDS exactly 40960 B => 4 blocks/CU.
__global__ __launch_bounds__(256) void flash_kernel(
    const short* __restrict__ q_r, const short* __restrict__ k_r,
    const short* __restrict__ v_t, float* __restrict__ Opart,
    float* __restrict__ mpart, float* __restrict__ lpart)
{
    const float SC = 0.08838834764831845f;
    int bid = blockIdx.x;
    int qt = 31 - (bid >> 5);
    int h  = (bid >> 1) & 15;
    int z  = bid & 1;
    int n  = qt + 1;
    int jhalf = (n + 1) >> 1;
    int jb = z ? jhalf : 0;
    int je = z ? n : jhalf;

    int tid = threadIdx.x, lane = tid & 63, wv = tid >> 6;
    int quad = lane >> 4, lm = lane & 15;

    __shared__ short lK[64 * 128];    // 16384 B
    __shared__ short lV[128 * 64];    // 16384 B
    __shared__ short lP[64 * 64];     // 8192 B, slot-rotated

    const short* qb = q_r + h * 262144 + (qt * 64 + wv * 16) * 128;
    const short* kb = k_r + h * 262144;
    const short* vb = v_t + h * 128 * 2048;

    bf16x8 aq[4];
#pragma unroll
    for (int kc = 0; kc < 4; kc++)
        aq[kc] = *(const bf16x8*)(qb + lm * 128 + kc * 32 + quad * 8);

    f32x4 ao[8];
#pragma unroll
    for (int nt = 0; nt < 8; nt++)
#pragma unroll
        for (int r = 0; r < 4; r++) ao[nt][r] = 0.0f;
    float mrow[4], lrow[4];
#pragma unroll
    for (int r = 0; r < 4; r++) { mrow[r] = -1e30f; lrow[r] = 0.0f; }

    if (jb < je) {
        // prologue: stage K_{jb}
#pragma unroll
        for (int i = 0; i < 4; i++) {
            int ci = i * 256 + tid;
            int r = ci >> 4, cp = ci & 15;
            int c = (cp & 8) | ((cp & 7) ^ (r & 7));
            const short* gp = kb + (jb * 64 + r) * 128 + c * 8;
            __builtin_amdgcn_global_load_lds((gmem_void*)gp, (lds_void*)(lK + ci * 8), 16, 0, 0);
        }
    }
    __syncthreads();

    for (int jt = jb; jt < je; jt++) {
        // 1. issue V_jt
#pragma unroll
        for (int i = 0; i < 4; i++) {
            int ci = i * 256 + tid;
            int r = ci >> 3, cp = ci & 7;
            int c = cp ^ (r & 7);
            const short* gp = vb + r * 2048 + jt * 64 + c * 8;
            __builtin_amdgcn_global_load_lds((gmem_void*)gp, (lds_void*)(lV + ci * 8), 16, 0, 0);
        }
        // 2. S = Q K^T
        f32x4 as[4];
#pragma unroll
        for (int nt = 0; nt < 4; nt++)
#pragma unroll
            for (int r = 0; r < 4; r++) as[nt][r] = 0.0f;
#pragma unroll
        for (int kc = 0; kc < 4; kc++) {
#pragma unroll
            for (int nt = 0; nt < 4; nt++) {
                int r = nt * 16 + lm;
                int c = kc * 4 + quad;
                int slot = (c & 8) | ((c & 7) ^ (r & 7));
                bf16x8 bk = *(const bf16x8*)(lK + (r * 16 + slot) * 8);
                as[nt] = __builtin_amdgcn_mfma_f32_16x16x32_bf16(aq[kc], bk, as[nt], 0, 0, 0);
            }
        }
        // 3. scale + diag mask + online softmax + P->lP (slot-rotated)
        bool diag = (jt == qt);
#pragma unroll
        for (int nt = 0; nt < 4; nt++)
#pragma unroll
            for (int r = 0; r < 4; r++) {
                float s = as[nt][r] * SC;
                if (diag) {
                    int qg = wv * 16 + quad * 4 + r;
                    int tg = nt * 16 + lm;
                    if (tg > qg) s = -1e30f;
                }
                as[nt][r] = s;
            }
#pragma unroll
        for (int r = 0; r < 4; r++) {
            float mx = fmaxf(fmaxf(as[0][r], as[1][r]), fmaxf(as[2][r], as[3][r]));
#pragma unroll
            for (int off = 1; off < 16; off <<= 1) mx = fmaxf(mx, __shfl_xor(mx, off));
            float mnew = fmaxf(mrow[r], mx);
            float alpha = __expf(mrow[r] - mnew);
            mrow[r] = mnew;
            float psum = 0.0f;
#pragma unroll
            for (int nt = 0; nt < 4; nt++) {
                float p = __expf(as[nt][r] - mnew);
                as[nt][r] = p;
                psum += p;
            }
#pragma unroll
            for (int off = 1; off < 16; off <<= 1) psum += __shfl_xor(psum, off);
            lrow[r] = lrow[r] * alpha + psum;
#pragma unroll
            for (int nt = 0; nt < 8; nt++) ao[nt][r] *= alpha;
            int row = wv * 16 + quad * 4 + r;
#pragma unroll
            for (int nt = 0; nt < 4; nt++) {
                int slot = (nt * 2 + (lm >> 3) + row) & 7;
                lP[row * 64 + slot * 8 + (lm & 7)] = f2bf(as[nt][r]);
            }
        }
        // 4. barrier: V arrived, lP visible, lK free
        __syncthreads();
        // 5. issue K_{jt+1}
        if (jt + 1 < je) {
#pragma unroll
            for (int i = 0; i < 4; i++) {
                int ci = i * 256 + tid;
                int r = ci >> 4, cp = ci & 15;
                int c = (cp & 8) | ((cp & 7) ^ (r & 7));
                const short* gp = kb + ((jt + 1) * 64 + r) * 128 + c * 8;
                __builtin_amdgcn_global_load_lds((gmem_void*)gp, (lds_void*)(lK + ci * 8), 16, 0, 0);
            }
        }
        // 6. O += P V^T
#pragma unroll
        for (int kt = 0; kt < 2; kt++) {
            int prow = wv * 16 + lm;
            int slot = (kt * 4 + quad + prow) & 7;
            bf16x8 ap = *(const bf16x8*)(lP + prow * 64 + slot * 8);
#pragma unroll
            for (int nt = 0; nt < 8; nt++) {
                int r = nt * 16 + lm;
                int c = kt * 4 + quad;
                int vslot = c ^ (r & 7);
                bf16x8 bv = *(const bf16x8*)(lV + (r * 8 + vslot) * 8);
                ao[nt] = __builtin_amdgcn_mfma_f32_16x16x32_bf16(ap, bv, ao[nt], 0, 0, 0);
            }
        }
        // 7. barrier: K_{jt+1} arrived, lV/lP free
        __syncthreads();
    }
    // epilogue: unnormalized partials
    float* Ob = Opart + (long long)z * 4194304;
#pragma unroll
    for (int r = 0; r < 4; r++) {
        int sg = qt * 64 + wv * 16 + quad * 4 + r;
#pragma unroll
        for (int nt = 0; nt < 8; nt++) {
            int dg = h * 128 + nt * 16 + lm;
            Ob[(long long)sg * 2048 + dg] = ao[nt][r];
        }
        if (lm == 0) {
            mpart[z * 32768 + h * 2048 + sg] = mrow[r];
            lpart[z * 32768 + h * 2048 + sg] = lrow[r];
        }
    }
}

// ---------------------------------------------------------------- combine
// merge 2 j-split partials -> attn bf16; 4 elems/thread
__global__ __launch_bounds__(256) void combine_kernel(
    const float* __restrict__ O0, const float* __restrict__ O1,
    const float* __restrict__ mpart, const float* __restrict__ lpart,
    short* __restrict__ attn)
{
    int idx = blockIdx.x * 256 + threadIdx.x;   // 1M threads
    int e = idx * 4;
    int s = e >> 11, h = (e & 2047) >> 7;
    float m0 = mpart[h * 2048 + s], m1 = mpart[32768 + h * 2048 + s];
    float l0 = lpart[h * 2048 + s], l1 = lpart[32768 + h * 2048 + s];
    float M = fmaxf(m0, m1);
    float w0 = __expf(m0 - M), w1 = __expf(m1 - M);
    float inv = 1.0f / (l0 * w0 + l1 * w1);
    float4 a = *(const float4*)(O0 + e);
    float4 b = *(const float4*)(O1 + e);
    short4 o;
    o.x = f2bf((a.x * w0 + b.x * w1) * inv);
    o.y = f2bf((a.y * w0 + b.y * w1) * inv);
    o.z = f2bf((a.z * w0 + b.z * w1) * inv);
    o.w = f2bf((a.w * w0 + b.w * w1) * inv);
    *(short4*)(attn + e) = o;
}

// ---------------------------------------------------------------- launch
extern "C" void kernel_launch(void* const* d_in, const int* in_sizes, int n_in,
                              void* d_out, int out_size, void* d_ws, size_t ws_size,
                              hipStream_t stream)
{
    const void* x  = d_in[0];
    const void* wq = d_in[2];
    const void* wk = d_in[3];
    const void* wv = d_in[4];
    const void* wo = d_in[5];

    char* ws = (char*)d_ws;
    size_t off = 0;
    auto alloc = [&](size_t b) { void* p = ws + off; off += (b + 255) & ~(size_t)255; return p; };
    short* wqkv_q = (short*)alloc(25165824);   // [6144][2048] bf16 (q,k,v)
    short* wo_q   = (short*)alloc(8388608);
    float* qkv    = (float*)alloc(50331648);   // [2048][6144] fp32
    short* v_t    = (short*)alloc(8388608);    // [o][t]
    short* q_r    = (short*)alloc(8388608);    // [h][s][128]
    short* k_r    = (short*)alloc(8388608);
    short* attn   = (short*)alloc(8388608);    // [s][2048]
    short* x_bf   = (short*)alloc(8388608);
    float* Opart  = (float*)alloc(33554432);   // [2][2048][2048] fp32
    float* mpart  = (float*)alloc(262144);     // [2][16][2048]
    float* lpart  = (float*)alloc(262144);
    int*   flag   = (int*)alloc(256);
    if (off > ws_size) return;                 // ~161 MB

    zero_flag<<<1, 64, 0, stream>>>(flag);
    detect_kernel<<<256, 256, 0, stream>>>(
        (const unsigned short*)x, in_sizes[0], flag);
    convert_kernel<<<16384, 256, 0, stream>>>(x, x_bf, 4194304, flag);

    quant_kernel<<<32768, 256, 0, stream>>>(wq, wk, wv, wo,
        wqkv_q, wqkv_q + 4194304, wqkv_q + 8388608, wo_q, flag);

    // QKV fused projection: [2048][6144] fp32
    gemm_bt<0,false,false><<<dim3(48,16,1), 256, 0, stream>>>(
        x_bf, wqkv_q, qkv, 2048,6144,2048, 2048,2048,6144, 1.0f, 0,0,0);

    rope_kernel<<<8192, 256, 0, stream>>>(qkv, q_r, k_r);
    vtrans_kernel<<<dim3(32,32), 256, 0, stream>>>(qkv, v_t);

    flash_kernel<<<1024, 256, 0, stream>>>(q_r, k_r, v_t, Opart, mpart, lpart);
    combine_kernel<<<4096, 256, 0, stream>>>(
        Opart, Opart + 4194304, mpart, lpart, attn);

    gemm_bt<0,false,false><<<dim3(16,16,1), 256, 0, stream>>>(
        attn, wo_q, d_out, 2048,2048,2048, 2048,2048,2048, 1.0f, 0,0,0);
}

// Round 8
// 333.859 us; speedup vs baseline: 1.3741x; 1.0007x over previous
//
#include <hip/hip_runtime.h>
#include <cstdint>
#include <cstddef>

// BitLlamaAttention: B=1, S=2048, HIDDEN=2048, NH=16, HD=128, GROUP=128
// Inputs fp32, output fp32. r7 @334us: gemm_qkv 67.5, flash 66.4,
// WO gemm ~50 (1 block/CU!), vtrans+rope+quant+combine tail.
// r8 (safe wins only; flash untouched):
//   - gemm_qkv epilogue: q/k -> bf16 [2048][4096], v -> transposed bf16 v_t
//     directly (r4-verified OM=2 pattern). vtrans kernel deleted; qkv write
//     traffic halved; rope reads bf16.
//   - WO gemm: 128x64 tiles, grid(32,16)=512 blocks=2/CU (was 256=1/CU).

typedef __attribute__((ext_vector_type(8))) short bf16x8;
typedef __attribute__((ext_vector_type(4))) float f32x4;
typedef __attribute__((address_space(3))) void lds_void;
typedef const __attribute__((address_space(1))) void gmem_void;

__device__ __forceinline__ short f2bf(float x) {
    union { float f; uint32_t u; } c; c.f = x;
    uint32_t r = (c.u + 0x7FFFu + ((c.u >> 16) & 1u)) >> 16;
    return (short)r;
}
__device__ __forceinline__ float bf2f(short x) {
    union { uint32_t u; float f; } c; c.u = ((uint32_t)(uint16_t)x) << 16;
    return c.f;
}

// ------------------------------------------------------------ dtype probe
__global__ __launch_bounds__(64) void zero_flag(int* f) {
    if (threadIdx.x == 0) *f = 0;
}

__global__ __launch_bounds__(256) void detect_kernel(
    const unsigned short* __restrict__ p, int n, int* __restrict__ flag)
{
    int tid = blockIdx.x * 256 + threadIdx.x;
    int cnt = 0;
    for (int i = tid; i < n; i += 65536) {
        int e = (p[i] >> 7) & 0xFF;
        cnt += (e >= 0xF0) ? 1 : 0;
    }
#pragma unroll
    for (int off = 1; off < 64; off <<= 1) cnt += __shfl_xor(cnt, off);
    if ((threadIdx.x & 63) == 0 && cnt) atomicAdd(flag, cnt);
}

__global__ __launch_bounds__(256) void convert_kernel(
    const void* __restrict__ in, short* __restrict__ out, int n,
    const int* __restrict__ flag)
{
    bool isf32 = (*flag > 1000);
    int i = blockIdx.x * 256 + threadIdx.x;
    if (i >= n) return;
    out[i] = isf32 ? f2bf(((const float*)in)[i]) : ((const short*)in)[i];
}

// ---------------------------------------------------------------- quantize
__global__ __launch_bounds__(256) void quant_kernel(
    const void* __restrict__ w0, const void* __restrict__ w1,
    const void* __restrict__ w2, const void* __restrict__ w3,
    short* __restrict__ q0, short* __restrict__ q1,
    short* __restrict__ q2, short* __restrict__ q3,
    const int* __restrict__ flag)
{
    bool isf32 = (*flag > 1000);
    int gw   = blockIdx.x * 4 + (threadIdx.x >> 6);
    int lane = threadIdx.x & 63;
    int mat  = gw >> 15;
    int g    = gw & 32767;
    const void* w = (mat == 0) ? w0 : (mat == 1) ? w1 : (mat == 2) ? w2 : w3;
    short*      q = (mat == 0) ? q0 : (mat == 1) ? q1 : (mat == 2) ? q2 : q3;
    int idx = g * 64 + lane;                       // index of element PAIR
    float a, b;
    if (isf32) {
        const float* wf = (const float*)w;
        a = wf[idx * 2]; b = wf[idx * 2 + 1];
    } else {
        int pr = ((const int*)w)[idx];
        a = bf2f((short)(pr & 0xFFFF));
        b = bf2f((short)(((uint32_t)pr) >> 16));
    }
    float s = fabsf(a) + fabsf(b);
#pragma unroll
    for (int off = 1; off < 64; off <<= 1) s += __shfl_xor(s, off);
    float scale = fmaxf(s * (1.0f / 128.0f), 1e-8f);
    float na = a / scale, nb = b / scale;
    float ra = (na > 0.5f) ? scale : (na < -0.5f) ? -scale : 0.0f;
    float rb = (nb > 0.5f) ? scale : (nb < -0.5f) ? -scale : 0.0f;
    ((int*)q)[idx] = (int)(uint16_t)f2bf(ra) | ((int)(uint16_t)f2bf(rb) << 16);
}

// ---------------------------------------------------------------- QKV GEMM
// C = x_bf[2048x2048] @ wqkv^T[6144x2048]. grid(48,16). bx<32: bf16 row-major
// into qk[2048][4096]; bx>=32: bf16 transposed into v_t[o=2048][t=2048].
__global__ __launch_bounds__(256) void gemm_qkv(
    const short* __restrict__ A, const short* __restrict__ B,
    short* __restrict__ Cqk, short* __restrict__ Cv)
{
    int bx = blockIdx.x, by = blockIdx.y;
    const short* Ab = A + (long long)by * 128 * 2048;
    const short* Bb = B + (long long)bx * 128 * 2048;
    __shared__ short lA[128 * 64];
    __shared__ short lB[128 * 64];
    int tid = threadIdx.x;
    int lane = tid & 63, wv = tid >> 6;
    f32x4 acc[4][4];
#pragma unroll
    for (int i = 0; i < 4; i++)
#pragma unroll
        for (int j = 0; j < 4; j++)
#pragma unroll
            for (int r = 0; r < 4; r++) acc[i][j][r] = 0.0f;

    int rbase = (wv >> 1) * 64, cbase = (wv & 1) * 64;

    for (int k0 = 0; k0 < 2048; k0 += 64) {
        __syncthreads();
#pragma unroll
        for (int i = 0; i < 4; i++) {
            int ci  = i * 256 + tid;
            int row = ci >> 3;
            int kcG = (ci & 7) ^ (row & 7);
            const short* gp = Ab + (long long)row * 2048 + k0 + kcG * 8;
            __builtin_amdgcn_global_load_lds((gmem_void*)gp, (lds_void*)(lA + ci * 8), 16, 0, 0);
        }
#pragma unroll
        for (int i = 0; i < 4; i++) {
            int ci  = i * 256 + tid;
            int row = ci >> 3;
            int kcG = (ci & 7) ^ (row & 7);
            const short* gp = Bb + (long long)row * 2048 + k0 + kcG * 8;
            __builtin_amdgcn_global_load_lds((gmem_void*)gp, (lds_void*)(lB + ci * 8), 16, 0, 0);
        }
        __syncthreads();
#pragma unroll
        for (int kk = 0; kk < 2; kk++) {
            int kc = kk * 4 + (lane >> 4);
            bf16x8 a[4], b[4];
#pragma unroll
            for (int t = 0; t < 4; t++) {
                int r = rbase + t * 16 + (lane & 15);
                a[t] = *(const bf16x8*)(lA + (r * 8 + (kc ^ (r & 7))) * 8);
            }
#pragma unroll
            for (int t = 0; t < 4; t++) {
                int r = cbase + t * 16 + (lane & 15);
                b[t] = *(const bf16x8*)(lB + (r * 8 + (kc ^ (r & 7))) * 8);
            }
#pragma unroll
            for (int mt = 0; mt < 4; mt++)
#pragma unroll
                for (int nt = 0; nt < 4; nt++)
                    acc[mt][nt] = __builtin_amdgcn_mfma_f32_16x16x32_bf16(a[mt], b[nt], acc[mt][nt], 0, 0, 0);
        }
    }

    int rq = (lane >> 4) * 4, cq = lane & 15;
    if (bx < 32) {
#pragma unroll
        for (int mt = 0; mt < 4; mt++)
#pragma unroll
            for (int nt = 0; nt < 4; nt++)
#pragma unroll
                for (int r = 0; r < 4; r++) {
                    int row = by * 128 + rbase + mt * 16 + rq + r;
                    int col = bx * 128 + cbase + nt * 16 + cq;
                    Cqk[(long long)row * 4096 + col] = f2bf(acc[mt][nt][r]);
                }
    } else {
#pragma unroll
        for (int mt = 0; mt < 4; mt++)
#pragma unroll
            for (int nt = 0; nt < 4; nt++)
#pragma unroll
                for (int r = 0; r < 4; r++) {
                    int row = by * 128 + rbase + mt * 16 + rq + r;
                    int colv = (bx - 32) * 128 + cbase + nt * 16 + cq;
                    Cv[(long long)colv * 2048 + row] = f2bf(acc[mt][nt][r]);
                }
    }
}

// ---------------------------------------------------------------- WO GEMM
// d_out[2048][2048] fp32 = attn[2048][2048]bf16 @ wo_q^T. 128x64 tiles,
// grid(32,16)=512 blocks (2/CU). Same verified core, BN=64.
__global__ __launch_bounds__(256) void gemm_wo(
    const short* __restrict__ A, const short* __restrict__ B,
    float* __restrict__ C)
{
    int bx = blockIdx.x, by = blockIdx.y;
    const short* Ab = A + (long long)by * 128 * 2048;
    const short* Bb = B + (long long)bx * 64 * 2048;
    __shared__ short lA[128 * 64];
    __shared__ short lB[64 * 64];
    int tid = threadIdx.x;
    int lane = tid & 63, wv = tid >> 6;
    f32x4 acc[2][4];
#pragma unroll
    for (int i = 0; i < 2; i++)
#pragma unroll
        for (int j = 0; j < 4; j++)
#pragma unroll
            for (int r = 0; r < 4; r++) acc[i][j][r] = 0.0f;

    int rbase = wv * 32;

    for (int k0 = 0; k0 < 2048; k0 += 64) {
        __syncthreads();
#pragma unroll
        for (int i = 0; i < 4; i++) {
            int ci  = i * 256 + tid;
            int row = ci >> 3;
            int kcG = (ci & 7) ^ (row & 7);
            const short* gp = Ab + (long long)row * 2048 + k0 + kcG * 8;
            __builtin_amdgcn_global_load_lds((gmem_void*)gp, (lds_void*)(lA + ci * 8), 16, 0, 0);
        }
#pragma unroll
        for (int i = 0; i < 2; i++) {
            int ci  = i * 256 + tid;
            int row = ci >> 3;
            int kcG = (ci & 7) ^ (row & 7);
            const short* gp = Bb + (long long)row * 2048 + k0 + kcG * 8;
            __builtin_amdgcn_global_load_lds((gmem_void*)gp, (lds_void*)(lB + ci * 8), 16, 0, 0);
        }
        __syncthreads();
#pragma unroll
        for (int kk = 0; kk < 2; kk++) {
            int kc = kk * 4 + (lane >> 4);
            bf16x8 a[2], b[4];
#pragma unroll
            for (int t = 0; t < 2; t++) {
                int r = rbase + t * 16 + (lane & 15);
                a[t] = *(const bf16x8*)(lA + (r * 8 + (kc ^ (r & 7))) * 8);
            }
#pragma unroll
            for (int t = 0; t < 4; t++) {
                int r = t * 16 + (lane & 15);
                b[t] = *(const bf16x8*)(lB + (r * 8 + (kc ^ (r & 7))) * 8);
            }
#pragma unroll
            for (int mt = 0; mt < 2; mt++)
#pragma unroll
                for (int nt = 0; nt < 4; nt++)
                    acc[mt][nt] = __builtin_amdgcn_mfma_f32_16x16x32_bf16(a[mt], b[nt], acc[mt][nt], 0, 0, 0);
        }
    }

    int rq = (lane >> 4) * 4, cq = lane & 15;
#pragma unroll
    for (int mt = 0; mt < 2; mt++)
#pragma unroll
        for (int nt = 0; nt < 4; nt++)
#pragma unroll
            for (int r = 0; r < 4; r++) {
                int row = by * 128 + rbase + mt * 16 + rq + r;
                int col = bx * 64 + nt * 16 + cq;
                C[(long long)row * 2048 + col] = acc[mt][nt][r];
            }
}

// ---------------------------------------------------------------- RoPE
// reads bf16 qk [2048][4096] (q cols 0..2047, k cols 2048..4095)
__global__ __launch_bounds__(256) void rope_kernel(
    const short* __restrict__ qk,
    short* __restrict__ qr, short* __restrict__ kr)
{
    int idx = blockIdx.x * 256 + threadIdx.x;      // 2048*16*64 = 2M
    int d = idx & 63;
    int h = (idx >> 6) & 15;
    int s = idx >> 10;
    float inv = exp2f((float)d * -0.20762050593261719f); // 10000^(-d/64)
    float ang = (float)s * inv;
    float sn, c;
    sincosf(ang, &sn, &c);
    long long io = (long long)s * 4096 + h * 128 + d;
    long long oo = (long long)h * 262144 + (long long)s * 128 + d;
    float x1 = bf2f(qk[io]), x2 = bf2f(qk[io + 64]);
    qr[oo]      = f2bf(x1 * c - x2 * sn);
    qr[oo + 64] = f2bf(x1 * sn + x2 * c);
    x1 = bf2f(qk[io + 2048]); x2 = bf2f(qk[io + 2112]);
    kr[oo]      = f2bf(x1 * c - x2 * sn);
    kr[oo + 64] = f2bf(x1 * sn + x2 * c);
}

// ---------------------------------------------------------------- flash attn
// (unchanged from r7) 1024 blocks: qt = 31-(bid>>5), h = (bid>>1)&15,
// z = bid&1 j-half. Unnormalized fp32 O-partials + (m,l). LDS 40960 B.
__global__ __launch_bounds__(256) void flash_kernel(
    const short* __restrict__ q_r, const short* __restrict__ k_r,
    const short* __restrict__ v_t, float* __restrict__ Opart,
    float* __restrict__ mpart, float* __restrict__ lpart)
{
    const float SC = 0.08838834764831845f;
    int bid = blockIdx.x;
    int qt = 31 - (bid >> 5);
    int h  = (bid >> 1) & 15;
    int z  = bid & 1;
    int n  = qt + 1;
    int jhalf = (n + 1) >> 1;
    int jb = z ? jhalf : 0;
    int je = z ? n : jhalf;

    int tid = threadIdx.x, lane = tid & 63, wv = tid >> 6;
    int quad = lane >> 4, lm = lane & 15;

    __shared__ short lK[64 * 128];
    __shared__ short lV[128 * 64];
    __shared__ short lP[64 * 64];

    const short* qb = q_r + h * 262144 + (qt * 64 + wv * 16) * 128;
    const short* kb = k_r + h * 262144;
    const short* vb = v_t + h * 128 * 2048;

    bf16x8 aq[4];
#pragma unroll
    for (int kc = 0; kc < 4; kc++)
        aq[kc] = *(const bf16x8*)(qb + lm * 128 + kc * 32 + quad * 8);

    f32x4 ao[8];
#pragma unroll
    for (int nt = 0; nt < 8; nt++)
#pragma unroll
        for (int r = 0; r < 4; r++) ao[nt][r] = 0.0f;
    float mrow[4], lrow[4];
#pragma unroll
    for (int r = 0; r < 4; r++) { mrow[r] = -1e30f; lrow[r] = 0.0f; }

    if (jb < je) {
#pragma unroll
        for (int i = 0; i < 4; i++) {
            int ci = i * 256 + tid;
            int r = ci >> 4, cp = ci & 15;
            int c = (cp & 8) | ((cp & 7) ^ (r & 7));
            const short* gp = kb + (jb * 64 + r) * 128 + c * 8;
            __builtin_amdgcn_global_load_lds((gmem_void*)gp, (lds_void*)(lK + ci * 8), 16, 0, 0);
        }
    }
    __syncthreads();

    for (int jt = jb; jt < je; jt++) {
#pragma unroll
        for (int i = 0; i < 4; i++) {
            int ci = i * 256 + tid;
            int r = ci >> 3, cp = ci & 7;
            int c = cp ^ (r & 7);
            const short* gp = vb + r * 2048 + jt * 64 + c * 8;
            __builtin_amdgcn_global_load_lds((gmem_void*)gp, (lds_void*)(lV + ci * 8), 16, 0, 0);
        }
        f32x4 as[4];
#pragma unroll
        for (int nt = 0; nt < 4; nt++)
#pragma unroll
            for (int r = 0; r < 4; r++) as[nt][r] = 0.0f;
#pragma unroll
        for (int kc = 0; kc < 4; kc++) {
#pragma unroll
            for (int nt = 0; nt < 4; nt++) {
                int r = nt * 16 + lm;
                int c = kc * 4 + quad;
                int slot = (c & 8) | ((c & 7) ^ (r & 7));
                bf16x8 bk = *(const bf16x8*)(lK + (r * 16 + slot) * 8);
                as[nt] = __builtin_amdgcn_mfma_f32_16x16x32_bf16(aq[kc], bk, as[nt], 0, 0, 0);
            }
        }
        bool diag = (jt == qt);
#pragma unroll
        for (int nt = 0; nt < 4; nt++)
#pragma unroll
            for (int r = 0; r < 4; r++) {
                float s = as[nt][r] * SC;
                if (diag) {
                    int qg = wv * 16 + quad * 4 + r;
                    int tg = nt * 16 + lm;
                    if (tg > qg) s = -1e30f;
                }
                as[nt][r] = s;
            }
#pragma unroll
        for (int r = 0; r < 4; r++) {
            float mx = fmaxf(fmaxf(as[0][r], as[1][r]), fmaxf(as[2][r], as[3][r]));
#pragma unroll
            for (int off = 1; off < 16; off <<= 1) mx = fmaxf(mx, __shfl_xor(mx, off));
            float mnew = fmaxf(mrow[r], mx);
            float alpha = __expf(mrow[r] - mnew);
            mrow[r] = mnew;
            float psum = 0.0f;
#pragma unroll
            for (int nt = 0; nt < 4; nt++) {
                float p = __expf(as[nt][r] - mnew);
                as[nt][r] = p;
                psum += p;
            }
#pragma unroll
            for (int off = 1; off < 16; off <<= 1) psum += __shfl_xor(psum, off);
            lrow[r] = lrow[r] * alpha + psum;
#pragma unroll
            for (int nt = 0; nt < 8; nt++) ao[nt][r] *= alpha;
            int row = wv * 16 + quad * 4 + r;
#pragma unroll
            for (int nt = 0; nt < 4; nt++) {
                int slot = (nt * 2 + (lm >> 3) + row) & 7;
                lP[row * 64 + slot * 8 + (lm & 7)] = f2bf(as[nt][r]);
            }
        }
        __syncthreads();
        if (jt + 1 < je) {
#pragma unroll
            for (int i = 0; i < 4; i++) {
                int ci = i * 256 + tid;
                int r = ci >> 4, cp = ci & 15;
                int c = (cp & 8) | ((cp & 7) ^ (r & 7));
                const short* gp = kb + ((jt + 1) * 64 + r) * 128 + c * 8;
                __builtin_amdgcn_global_load_lds((gmem_void*)gp, (lds_void*)(lK + ci * 8), 16, 0, 0);
            }
        }
#pragma unroll
        for (int kt = 0; kt < 2; kt++) {
            int prow = wv * 16 + lm;
            int slot = (kt * 4 + quad + prow) & 7;
            bf16x8 ap = *(const bf16x8*)(lP + prow * 64 + slot * 8);
#pragma unroll
            for (int nt = 0; nt < 8; nt++) {
                int r = nt * 16 + lm;
                int c = kt * 4 + quad;
                int vslot = c ^ (r & 7);
                bf16x8 bv = *(const bf16x8*)(lV + (r * 8 + vslot) * 8);
                ao[nt] = __builtin_amdgcn_mfma_f32_16x16x32_bf16(ap, bv, ao[nt], 0, 0, 0);
            }
        }
        __syncthreads();
    }
    float* Ob = Opart + (long long)z * 4194304;
#pragma unroll
    for (int r = 0; r < 4; r++) {
        int sg = qt * 64 + wv * 16 + quad * 4 + r;
#pragma unroll
        for (int nt = 0; nt < 8; nt++) {
            int dg = h * 128 + nt * 16 + lm;
            Ob[(long long)sg * 2048 + dg] = ao[nt][r];
        }
        if (lm == 0) {
            mpart[z * 32768 + h * 2048 + sg] = mrow[r];
            lpart[z * 32768 + h * 2048 + sg] = lrow[r];
        }
    }
}

// ---------------------------------------------------------------- combine
__global__ __launch_bounds__(256) void combine_kernel(
    const float* __restrict__ O0, const float* __restrict__ O1,
    const float* __restrict__ mpart, const float* __restrict__ lpart,
    short* __restrict__ attn)
{
    int idx = blockIdx.x * 256 + threadIdx.x;   // 1M threads
    int e = idx * 4;
    int s = e >> 11, h = (e & 2047) >> 7;
    float m0 = mpart[h * 2048 + s], m1 = mpart[32768 + h * 2048 + s];
    float l0 = lpart[h * 2048 + s], l1 = lpart[32768 + h * 2048 + s];
    float M = fmaxf(m0, m1);
    float w0 = __expf(m0 - M), w1 = __expf(m1 - M);
    float inv = 1.0f / (l0 * w0 + l1 * w1);
    float4 a = *(const float4*)(O0 + e);
    float4 b = *(const float4*)(O1 + e);
    short4 o;
    o.x = f2bf((a.x * w0 + b.x * w1) * inv);
    o.y = f2bf((a.y * w0 + b.y * w1) * inv);
    o.z = f2bf((a.z * w0 + b.z * w1) * inv);
    o.w = f2bf((a.w * w0 + b.w * w1) * inv);
    *(short4*)(attn + e) = o;
}

// ---------------------------------------------------------------- launch
extern "C" void kernel_launch(void* const* d_in, const int* in_sizes, int n_in,
                              void* d_out, int out_size, void* d_ws, size_t ws_size,
                              hipStream_t stream)
{
    const void* x  = d_in[0];
    const void* wq = d_in[2];
    const void* wk = d_in[3];
    const void* wv = d_in[4];
    const void* wo = d_in[5];

    char* ws = (char*)d_ws;
    size_t off = 0;
    auto alloc = [&](size_t b) { void* p = ws + off; off += (b + 255) & ~(size_t)255; return p; };
    short* wqkv_q = (short*)alloc(25165824);   // [6144][2048] bf16 (q,k,v)
    short* wo_q   = (short*)alloc(8388608);
    short* qk     = (short*)alloc(16777216);   // [2048][4096] bf16 (q,k)
    short* v_t    = (short*)alloc(8388608);    // [o][t]
    short* q_r    = (short*)alloc(8388608);    // [h][s][128]
    short* k_r    = (short*)alloc(8388608);
    short* attn   = (short*)alloc(8388608);    // [s][2048]
    short* x_bf   = (short*)alloc(8388608);
    float* Opart  = (float*)alloc(33554432);   // [2][2048][2048] fp32
    float* mpart  = (float*)alloc(262144);     // [2][16][2048]
    float* lpart  = (float*)alloc(262144);
    int*   flag   = (int*)alloc(256);
    if (off > ws_size) return;                 // ~128 MB

    zero_flag<<<1, 64, 0, stream>>>(flag);
    detect_kernel<<<256, 256, 0, stream>>>(
        (const unsigned short*)x, in_sizes[0], flag);
    convert_kernel<<<16384, 256, 0, stream>>>(x, x_bf, 4194304, flag);

    quant_kernel<<<32768, 256, 0, stream>>>(wq, wk, wv, wo,
        wqkv_q, wqkv_q + 4194304, wqkv_q + 8388608, wo_q, flag);

    gemm_qkv<<<dim3(48,16), 256, 0, stream>>>(x_bf, wqkv_q, qk, v_t);

    rope_kernel<<<8192, 256, 0, stream>>>(qk, q_r, k_r);

    flash_kernel<<<1024, 256, 0, stream>>>(q_r, k_r, v_t, Opart, mpart, lpart);
    combine_kernel<<<4096, 256, 0, stream>>>(
        Opart, Opart + 4194304, mpart, lpart, attn);

    gemm_wo<<<dim3(32,16), 256, 0, stream>>>(attn, wo_q, (float*)d_out);
}

// Round 9
// 332.648 us; speedup vs baseline: 1.3791x; 1.0036x over previous
//
#include <hip/hip_runtime.h>
#include <cstdint>
#include <cstddef>

// BitLlamaAttention: B=1, S=2048, HIDDEN=2048, NH=16, HD=128, GROUP=128
// Inputs fp32, output fp32. r8 @334us: gemm_qkv REGRESSED to 84us — the
// direct-transposed V epilogue wrote uncoalesced u16 (lane varies along the
// row-stride axis). Flash conflicts (2.16M) localized to lP u16 writes
// (4*quad term spans only {0,4} mod 8 -> 4-way).
// r9:
//   - gemm_qkv: V blocks stage the 128x128 tile in LDS (reusing the 32KB
//     staging buffer post-barrier, chunk-xor swizzle) then write v_t rows
//     as coalesced bf16x8.
//   - flash lP swizzle: slot_w=(c+2*quad)&7 (uniform 8 slots; 2-way max).
//   - convert_kernel vectorized x4.

typedef __attribute__((ext_vector_type(8))) short bf16x8;
typedef __attribute__((ext_vector_type(4))) float f32x4;
typedef __attribute__((address_space(3))) void lds_void;
typedef const __attribute__((address_space(1))) void gmem_void;

__device__ __forceinline__ short f2bf(float x) {
    union { float f; uint32_t u; } c; c.f = x;
    uint32_t r = (c.u + 0x7FFFu + ((c.u >> 16) & 1u)) >> 16;
    return (short)r;
}
__device__ __forceinline__ float bf2f(short x) {
    union { uint32_t u; float f; } c; c.u = ((uint32_t)(uint16_t)x) << 16;
    return c.f;
}

// ------------------------------------------------------------ dtype probe
__global__ __launch_bounds__(64) void zero_flag(int* f) {
    if (threadIdx.x == 0) *f = 0;
}

__global__ __launch_bounds__(256) void detect_kernel(
    const unsigned short* __restrict__ p, int n, int* __restrict__ flag)
{
    int tid = blockIdx.x * 256 + threadIdx.x;
    int cnt = 0;
    for (int i = tid; i < n; i += 65536) {
        int e = (p[i] >> 7) & 0xFF;
        cnt += (e >= 0xF0) ? 1 : 0;
    }
#pragma unroll
    for (int off = 1; off < 64; off <<= 1) cnt += __shfl_xor(cnt, off);
    if ((threadIdx.x & 63) == 0 && cnt) atomicAdd(flag, cnt);
}

// canonicalize hidden_states to bf16, 4 elems/thread
__global__ __launch_bounds__(256) void convert_kernel(
    const void* __restrict__ in, short* __restrict__ out, int n,
    const int* __restrict__ flag)
{
    bool isf32 = (*flag > 1000);
    int i = (blockIdx.x * 256 + threadIdx.x) * 4;
    if (i >= n) return;
    if (isf32) {
        float4 v = *(const float4*)((const float*)in + i);
        short4 o;
        o.x = f2bf(v.x); o.y = f2bf(v.y); o.z = f2bf(v.z); o.w = f2bf(v.w);
        *(short4*)(out + i) = o;
    } else {
        *(short4*)(out + i) = *(const short4*)((const short*)in + i);
    }
}

// ---------------------------------------------------------------- quantize
__global__ __launch_bounds__(256) void quant_kernel(
    const void* __restrict__ w0, const void* __restrict__ w1,
    const void* __restrict__ w2, const void* __restrict__ w3,
    short* __restrict__ q0, short* __restrict__ q1,
    short* __restrict__ q2, short* __restrict__ q3,
    const int* __restrict__ flag)
{
    bool isf32 = (*flag > 1000);
    int gw   = blockIdx.x * 4 + (threadIdx.x >> 6);
    int lane = threadIdx.x & 63;
    int mat  = gw >> 15;
    int g    = gw & 32767;
    const void* w = (mat == 0) ? w0 : (mat == 1) ? w1 : (mat == 2) ? w2 : w3;
    short*      q = (mat == 0) ? q0 : (mat == 1) ? q1 : (mat == 2) ? q2 : q3;
    int idx = g * 64 + lane;                       // index of element PAIR
    float a, b;
    if (isf32) {
        const float* wf = (const float*)w;
        a = wf[idx * 2]; b = wf[idx * 2 + 1];
    } else {
        int pr = ((const int*)w)[idx];
        a = bf2f((short)(pr & 0xFFFF));
        b = bf2f((short)(((uint32_t)pr) >> 16));
    }
    float s = fabsf(a) + fabsf(b);
#pragma unroll
    for (int off = 1; off < 64; off <<= 1) s += __shfl_xor(s, off);
    float scale = fmaxf(s * (1.0f / 128.0f), 1e-8f);
    float na = a / scale, nb = b / scale;
    float ra = (na > 0.5f) ? scale : (na < -0.5f) ? -scale : 0.0f;
    float rb = (nb > 0.5f) ? scale : (nb < -0.5f) ? -scale : 0.0f;
    ((int*)q)[idx] = (int)(uint16_t)f2bf(ra) | ((int)(uint16_t)f2bf(rb) << 16);
}

// ---------------------------------------------------------------- QKV GEMM
// C = x_bf[2048x2048] @ wqkv^T[6144x2048]. grid(48,16). bx<32: bf16 row-major
// into qk[2048][4096]; bx>=32: LDS-transposed, coalesced bf16x8 rows of
// v_t[o=2048][t=2048].
__global__ __launch_bounds__(256) void gemm_qkv(
    const short* __restrict__ A, const short* __restrict__ B,
    short* __restrict__ Cqk, short* __restrict__ Cv)
{
    int bx = blockIdx.x, by = blockIdx.y;
    const short* Ab = A + (long long)by * 128 * 2048;
    const short* Bb = B + (long long)bx * 128 * 2048;
    __shared__ short ls[16384];                    // lA = ls, lB = ls+8192
    short* lA = ls;
    short* lB = ls + 8192;
    int tid = threadIdx.x;
    int lane = tid & 63, wv = tid >> 6;
    f32x4 acc[4][4];
#pragma unroll
    for (int i = 0; i < 4; i++)
#pragma unroll
        for (int j = 0; j < 4; j++)
#pragma unroll
            for (int r = 0; r < 4; r++) acc[i][j][r] = 0.0f;

    int rbase = (wv >> 1) * 64, cbase = (wv & 1) * 64;

    for (int k0 = 0; k0 < 2048; k0 += 64) {
        __syncthreads();
#pragma unroll
        for (int i = 0; i < 4; i++) {
            int ci  = i * 256 + tid;
            int row = ci >> 3;
            int kcG = (ci & 7) ^ (row & 7);
            const short* gp = Ab + (long long)row * 2048 + k0 + kcG * 8;
            __builtin_amdgcn_global_load_lds((gmem_void*)gp, (lds_void*)(lA + ci * 8), 16, 0, 0);
        }
#pragma unroll
        for (int i = 0; i < 4; i++) {
            int ci  = i * 256 + tid;
            int row = ci >> 3;
            int kcG = (ci & 7) ^ (row & 7);
            const short* gp = Bb + (long long)row * 2048 + k0 + kcG * 8;
            __builtin_amdgcn_global_load_lds((gmem_void*)gp, (lds_void*)(lB + ci * 8), 16, 0, 0);
        }
        __syncthreads();
#pragma unroll
        for (int kk = 0; kk < 2; kk++) {
            int kc = kk * 4 + (lane >> 4);
            bf16x8 a[4], b[4];
#pragma unroll
            for (int t = 0; t < 4; t++) {
                int r = rbase + t * 16 + (lane & 15);
                a[t] = *(const bf16x8*)(lA + (r * 8 + (kc ^ (r & 7))) * 8);
            }
#pragma unroll
            for (int t = 0; t < 4; t++) {
                int r = cbase + t * 16 + (lane & 15);
                b[t] = *(const bf16x8*)(lB + (r * 8 + (kc ^ (r & 7))) * 8);
            }
#pragma unroll
            for (int mt = 0; mt < 4; mt++)
#pragma unroll
                for (int nt = 0; nt < 4; nt++)
                    acc[mt][nt] = __builtin_amdgcn_mfma_f32_16x16x32_bf16(a[mt], b[nt], acc[mt][nt], 0, 0, 0);
        }
    }

    int rq = (lane >> 4) * 4, cq = lane & 15;
    if (bx < 32) {
#pragma unroll
        for (int mt = 0; mt < 4; mt++)
#pragma unroll
            for (int nt = 0; nt < 4; nt++)
#pragma unroll
                for (int r = 0; r < 4; r++) {
                    int row = by * 128 + rbase + mt * 16 + rq + r;
                    int col = bx * 128 + cbase + nt * 16 + cq;
                    Cqk[(long long)row * 4096 + col] = f2bf(acc[mt][nt][r]);
                }
    } else {
        // transpose through LDS: ls[col][row], row-chunk xor swizzle
        __syncthreads();                            // staging reads all done
#pragma unroll
        for (int mt = 0; mt < 4; mt++)
#pragma unroll
            for (int nt = 0; nt < 4; nt++)
#pragma unroll
                for (int r = 0; r < 4; r++) {
                    int row = rbase + mt * 16 + rq + r;   // t within tile
                    int col = cbase + nt * 16 + cq;       // o within tile
                    int rcs = (row >> 3) ^ (col & 15);
                    ls[col * 128 + rcs * 8 + (row & 7)] = f2bf(acc[mt][nt][r]);
                }
        __syncthreads();
        int o = tid >> 1, half = tid & 1;
        long long og = (long long)((bx - 32) * 128 + o) * 2048 + by * 128;
#pragma unroll
        for (int c = 0; c < 8; c++) {
            int ch = half * 8 + c;
            int chs = ch ^ (o & 15);
            bf16x8 v = *(const bf16x8*)(ls + o * 128 + chs * 8);
            *(bf16x8*)(Cv + og + ch * 8) = v;
        }
    }
}

// ---------------------------------------------------------------- WO GEMM
// d_out[2048][2048] fp32 = attn bf16 @ wo_q^T. 128x64 tiles, grid(32,16).
__global__ __launch_bounds__(256) void gemm_wo(
    const short* __restrict__ A, const short* __restrict__ B,
    float* __restrict__ C)
{
    int bx = blockIdx.x, by = blockIdx.y;
    const short* Ab = A + (long long)by * 128 * 2048;
    const short* Bb = B + (long long)bx * 64 * 2048;
    __shared__ short lA[128 * 64];
    __shared__ short lB[64 * 64];
    int tid = threadIdx.x;
    int lane = tid & 63, wv = tid >> 6;
    f32x4 acc[2][4];
#pragma unroll
    for (int i = 0; i < 2; i++)
#pragma unroll
        for (int j = 0; j < 4; j++)
#pragma unroll
            for (int r = 0; r < 4; r++) acc[i][j][r] = 0.0f;

    int rbase = wv * 32;

    for (int k0 = 0; k0 < 2048; k0 += 64) {
        __syncthreads();
#pragma unroll
        for (int i = 0; i < 4; i++) {
            int ci  = i * 256 + tid;
            int row = ci >> 3;
            int kcG = (ci & 7) ^ (row & 7);
            const short* gp = Ab + (long long)row * 2048 + k0 + kcG * 8;
            __builtin_amdgcn_global_load_lds((gmem_void*)gp, (lds_void*)(lA + ci * 8), 16, 0, 0);
        }
#pragma unroll
        for (int i = 0; i < 2; i++) {
            int ci  = i * 256 + tid;
            int row = ci >> 3;
            int kcG = (ci & 7) ^ (row & 7);
            const short* gp = Bb + (long long)row * 2048 + k0 + kcG * 8;
            __builtin_amdgcn_global_load_lds((gmem_void*)gp, (lds_void*)(lB + ci * 8), 16, 0, 0);
        }
        __syncthreads();
#pragma unroll
        for (int kk = 0; kk < 2; kk++) {
            int kc = kk * 4 + (lane >> 4);
            bf16x8 a[2], b[4];
#pragma unroll
            for (int t = 0; t < 2; t++) {
                int r = rbase + t * 16 + (lane & 15);
                a[t] = *(const bf16x8*)(lA + (r * 8 + (kc ^ (r & 7))) * 8);
            }
#pragma unroll
            for (int t = 0; t < 4; t++) {
                int r = t * 16 + (lane & 15);
                b[t] = *(const bf16x8*)(lB + (r * 8 + (kc ^ (r & 7))) * 8);
            }
#pragma unroll
            for (int mt = 0; mt < 2; mt++)
#pragma unroll
                for (int nt = 0; nt < 4; nt++)
                    acc[mt][nt] = __builtin_amdgcn_mfma_f32_16x16x32_bf16(a[mt], b[nt], acc[mt][nt], 0, 0, 0);
        }
    }

    int rq = (lane >> 4) * 4, cq = lane & 15;
#pragma unroll
    for (int mt = 0; mt < 2; mt++)
#pragma unroll
        for (int nt = 0; nt < 4; nt++)
#pragma unroll
            for (int r = 0; r < 4; r++) {
                int row = by * 128 + rbase + mt * 16 + rq + r;
                int col = bx * 64 + nt * 16 + cq;
                C[(long long)row * 2048 + col] = acc[mt][nt][r];
            }
}

// ---------------------------------------------------------------- RoPE
__global__ __launch_bounds__(256) void rope_kernel(
    const short* __restrict__ qk,
    short* __restrict__ qr, short* __restrict__ kr)
{
    int idx = blockIdx.x * 256 + threadIdx.x;      // 2048*16*64 = 2M
    int d = idx & 63;
    int h = (idx >> 6) & 15;
    int s = idx >> 10;
    float inv = exp2f((float)d * -0.20762050593261719f); // 10000^(-d/64)
    float ang = (float)s * inv;
    float sn, c;
    sincosf(ang, &sn, &c);
    long long io = (long long)s * 4096 + h * 128 + d;
    long long oo = (long long)h * 262144 + (long long)s * 128 + d;
    float x1 = bf2f(qk[io]), x2 = bf2f(qk[io + 64]);
    qr[oo]      = f2bf(x1 * c - x2 * sn);
    qr[oo + 64] = f2bf(x1 * sn + x2 * c);
    x1 = bf2f(qk[io + 2048]); x2 = bf2f(qk[io + 2112]);
    kr[oo]      = f2bf(x1 * c - x2 * sn);
    kr[oo + 64] = f2bf(x1 * sn + x2 * c);
}

// ---------------------------------------------------------------- flash attn
// 1024 blocks: qt = 31-(bid>>5), h = (bid>>1)&15, z = bid&1 j-half.
// Unnormalized fp32 O-partials + (m,l). LDS 40960 B => 4 blocks/CU.
// lP swizzle: slot_w=(c+2*quad)&7 -> uniform 8 slots, 2-way max (free).
__global__ __launch_bounds__(256) void flash_kernel(
    const short* __restrict__ q_r, const short* __restrict__ k_r,
    const short* __restrict__ v_t, float* __restrict__ Opart,
    float* __restrict__ mpart, float* __restrict__ lpart)
{
    const float SC = 0.08838834764831845f;
    int bid = blockIdx.x;
    int qt = 31 - (bid >> 5);
    int h  = (bid >> 1) & 15;
    int z  = bid & 1;
    int n  = qt + 1;
    int jhalf = (n + 1) >> 1;
    int jb = z ? jhalf : 0;
    int je = z ? n : jhalf;

    int tid = threadIdx.x, lane = tid & 63, wv = tid >> 6;
    int quad = lane >> 4, lm = lane & 15;

    __shared__ short lK[64 * 128];
    __shared__ short lV[128 * 64];
    __shared__ short lP[64 * 64];

    const short* qb = q_r + h * 262144 + (qt * 64 + wv * 16) * 128;
    const short* kb = k_r + h * 262144;
    const short* vb = v_t + h * 128 * 2048;

    bf16x8 aq[4];
#pragma unroll
    for (int kc = 0; kc < 4; kc++)
        aq[kc] = *(const bf16x8*)(qb + lm * 128 + kc * 32 + quad * 8);

    f32x4 ao[8];
#pragma unroll
    for (int nt = 0; nt < 8; nt++)
#pragma unroll
        for (int r = 0; r < 4; r++) ao[nt][r] = 0.0f;
    float mrow[4], lrow[4];
#pragma unroll
    for (int r = 0; r < 4; r++) { mrow[r] = -1e30f; lrow[r] = 0.0f; }

    if (jb < je) {
#pragma unroll
        for (int i = 0; i < 4; i++) {
            int ci = i * 256 + tid;
            int r = ci >> 4, cp = ci & 15;
            int c = (cp & 8) | ((cp & 7) ^ (r & 7));
            const short* gp = kb + (jb * 64 + r) * 128 + c * 8;
            __builtin_amdgcn_global_load_lds((gmem_void*)gp, (lds_void*)(lK + ci * 8), 16, 0, 0);
        }
    }
    __syncthreads();

    for (int jt = jb; jt < je; jt++) {
#pragma unroll
        for (int i = 0; i < 4; i++) {
            int ci = i * 256 + tid;
            int r = ci >> 3, cp = ci & 7;
            int c = cp ^ (r & 7);
            const short* gp = vb + r * 2048 + jt * 64 + c * 8;
            __builtin_amdgcn_global_load_lds((gmem_void*)gp, (lds_void*)(lV + ci * 8), 16, 0, 0);
        }
        f32x4 as[4];
#pragma unroll
        for (int nt = 0; nt < 4; nt++)
#pragma unroll
            for (int r = 0; r < 4; r++) as[nt][r] = 0.0f;
#pragma unroll
        for (int kc = 0; kc < 4; kc++) {
#pragma unroll
            for (int nt = 0; nt < 4; nt++) {
                int r = nt * 16 + lm;
                int c = kc * 4 + quad;
                int slot = (c & 8) | ((c & 7) ^ (r & 7));
                bf16x8 bk = *(const bf16x8*)(lK + (r * 16 + slot) * 8);
                as[nt] = __builtin_amdgcn_mfma_f32_16x16x32_bf16(aq[kc], bk, as[nt], 0, 0, 0);
            }
        }
        bool diag = (jt == qt);
#pragma unroll
        for (int nt = 0; nt < 4; nt++)
#pragma unroll
            for (int r = 0; r < 4; r++) {
                float s = as[nt][r] * SC;
                if (diag) {
                    int qg = wv * 16 + quad * 4 + r;
                    int tg = nt * 16 + lm;
                    if (tg > qg) s = -1e30f;
                }
                as[nt][r] = s;
            }
#pragma unroll
        for (int r = 0; r < 4; r++) {
            float mx = fmaxf(fmaxf(as[0][r], as[1][r]), fmaxf(as[2][r], as[3][r]));
#pragma unroll
            for (int off = 1; off < 16; off <<= 1) mx = fmaxf(mx, __shfl_xor(mx, off));
            float mnew = fmaxf(mrow[r], mx);
            float alpha = __expf(mrow[r] - mnew);
            mrow[r] = mnew;
            float psum = 0.0f;
#pragma unroll
            for (int nt = 0; nt < 4; nt++) {
                float p = __expf(as[nt][r] - mnew);
                as[nt][r] = p;
                psum += p;
            }
#pragma unroll
            for (int off = 1; off < 16; off <<= 1) psum += __shfl_xor(psum, off);
            lrow[r] = lrow[r] * alpha + psum;
#pragma unroll
            for (int nt = 0; nt < 8; nt++) ao[nt][r] *= alpha;
            int row = wv * 16 + quad * 4 + r;
#pragma unroll
            for (int nt = 0; nt < 4; nt++) {
                int slot = (nt * 2 + (lm >> 3) + 2 * quad) & 7;   // uniform
                lP[row * 64 + slot * 8 + (lm & 7)] = f2bf(as[nt][r]);
            }
        }
        __syncthreads();
        if (jt + 1 < je) {
#pragma unroll
            for (int i = 0; i < 4; i++) {
                int ci = i * 256 + tid;
                int r = ci >> 4, cp = ci & 15;
                int c = (cp & 8) | ((cp & 7) ^ (r & 7));
                const short* gp = kb + ((jt + 1) * 64 + r) * 128 + c * 8;
                __builtin_amdgcn_global_load_lds((gmem_void*)gp, (lds_void*)(lK + ci * 8), 16, 0, 0);
            }
        }
#pragma unroll
        for (int kt = 0; kt < 2; kt++) {
            int prow = wv * 16 + lm;
            int slot = (kt * 4 + quad + 2 * (lm >> 2)) & 7;       // matches write
            bf16x8 ap = *(const bf16x8*)(lP + prow * 64 + slot * 8);
#pragma unroll
            for (int nt = 0; nt < 8; nt++) {
                int r = nt * 16 + lm;
                int c = kt * 4 + quad;
                int vslot = c ^ (r & 7);
                bf16x8 bv = *(const bf16x8*)(lV + (r * 8 + vslot) * 8);
                ao[nt] = __builtin_amdgcn_mfma_f32_16x16x32_bf16(ap, bv, ao[nt], 0, 0, 0);
            }
        }
        __syncthreads();
    }
    float* Ob = Opart + (long long)z * 4194304;
#pragma unroll
    for (int r = 0; r < 4; r++) {
        int sg = qt * 64 + wv * 16 + quad * 4 + r;
#pragma unroll
        for (int nt = 0; nt < 8; nt++) {
            int dg = h * 128 + nt * 16 + lm;
            Ob[(long long)sg * 2048 + dg] = ao[nt][r];
        }
        if (lm == 0) {
            mpart[z * 32768 + h * 2048 + sg] = mrow[r];
            lpart[z * 32768 + h * 2048 + sg] = lrow[r];
        }
    }
}

// ---------------------------------------------------------------- combine
__global__ __launch_bounds__(256) void combine_kernel(
    const float* __restrict__ O0, const float* __restrict__ O1,
    const float* __restrict__ mpart, const float* __restrict__ lpart,
    short* __restrict__ attn)
{
    int idx = blockIdx.x * 256 + threadIdx.x;   // 1M threads
    int e = idx * 4;
    int s = e >> 11, h = (e & 2047) >> 7;
    float m0 = mpart[h * 2048 + s], m1 = mpart[32768 + h * 2048 + s];
    float l0 = lpart[h * 2048 + s], l1 = lpart[32768 + h * 2048 + s];
    float M = fmaxf(m0, m1);
    float w0 = __expf(m0 - M), w1 = __expf(m1 - M);
    float inv = 1.0f / (l0 * w0 + l1 * w1);
    float4 a = *(const float4*)(O0 + e);
    float4 b = *(const float4*)(O1 + e);
    short4 o;
    o.x = f2bf((a.x * w0 + b.x * w1) * inv);
    o.y = f2bf((a.y * w0 + b.y * w1) * inv);
    o.z = f2bf((a.z * w0 + b.z * w1) * inv);
    o.w = f2bf((a.w * w0 + b.w * w1) * inv);
    *(short4*)(attn + e) = o;
}

// ---------------------------------------------------------------- launch
extern "C" void kernel_launch(void* const* d_in, const int* in_sizes, int n_in,
                              void* d_out, int out_size, void* d_ws, size_t ws_size,
                              hipStream_t stream)
{
    const void* x  = d_in[0];
    const void* wq = d_in[2];
    const void* wk = d_in[3];
    const void* wv = d_in[4];
    const void* wo = d_in[5];

    char* ws = (char*)d_ws;
    size_t off = 0;
    auto alloc = [&](size_t b) { void* p = ws + off; off += (b + 255) & ~(size_t)255; return p; };
    short* wqkv_q = (short*)alloc(25165824);   // [6144][2048] bf16 (q,k,v)
    short* wo_q   = (short*)alloc(8388608);
    short* qk     = (short*)alloc(16777216);   // [2048][4096] bf16 (q,k)
    short* v_t    = (short*)alloc(8388608);    // [o][t]
    short* q_r    = (short*)alloc(8388608);    // [h][s][128]
    short* k_r    = (short*)alloc(8388608);
    short* attn   = (short*)alloc(8388608);    // [s][2048]
    short* x_bf   = (short*)alloc(8388608);
    float* Opart  = (float*)alloc(33554432);   // [2][2048][2048] fp32
    float* mpart  = (float*)alloc(262144);     // [2][16][2048]
    float* lpart  = (float*)alloc(262144);
    int*   flag   = (int*)alloc(256);
    if (off > ws_size) return;                 // ~128 MB

    zero_flag<<<1, 64, 0, stream>>>(flag);
    detect_kernel<<<256, 256, 0, stream>>>(
        (const unsigned short*)x, in_sizes[0], flag);
    convert_kernel<<<4096, 256, 0, stream>>>(x, x_bf, 4194304, flag);

    quant_kernel<<<32768, 256, 0, stream>>>(wq, wk, wv, wo,
        wqkv_q, wqkv_q + 4194304, wqkv_q + 8388608, wo_q, flag);

    gemm_qkv<<<dim3(48,16), 256, 0, stream>>>(x_bf, wqkv_q, qk, v_t);

    rope_kernel<<<8192, 256, 0, stream>>>(qk, q_r, k_r);

    flash_kernel<<<1024, 256, 0, stream>>>(q_r, k_r, v_t, Opart, mpart, lpart);
    combine_kernel<<<4096, 256, 0, stream>>>(
        Opart, Opart + 4194304, mpart, lpart, attn);

    gemm_wo<<<dim3(32,16), 256, 0, stream>>>(attn, wo_q, (float*)d_out);
}